// Round 5
// baseline (167.536 us; speedup 1.0000x reference)
//
#include <hip/hip_runtime.h>

typedef unsigned short u16;
typedef unsigned int u32;
typedef short short8 __attribute__((ext_vector_type(8)));
typedef float f32x4 __attribute__((ext_vector_type(4)));

#define B_ 4
#define N_ 2048
#define D_ 256
#define H_ 4
#define DH_ 64
#define BN_ 8192

__device__ inline float b2f(u16 u) {
    union { u32 i; float f; } v; v.i = ((u32)u) << 16; return v.f;
}
// round-half-up bf16: 2 VALU ops
__device__ inline u16 f2b(float f) {
    union { float f; u32 i; } v; v.f = f;
    return (u16)((v.i + 0x8000u) >> 16);
}
// pack two f32 -> bf16 pair (lo=a, hi=b) in 3 VALU via v_perm_b32
__device__ inline u32 pkbf(float a, float b) {
    union { float f; u32 i; } ua, ub; ua.f = a; ub.f = b;
    return __builtin_amdgcn_perm(ub.i + 0x8000u, ua.i + 0x8000u, 0x07060302u);
}
__device__ inline f32x4 mfma16(short8 a, short8 b, f32x4 c) {
    return __builtin_amdgcn_mfma_f32_16x16x32_bf16(a, b, c, 0, 0, 0);
}

// -------- MFMA GEMM, qkv: block=128x64 (4 waves x 64x32) --------------------
// Round-4 post-mortem: old 128x128 grid was 384 blocks on 256 CUs -> half the
// CUs ran 2 blocks, half ran 1 (33% straggler waste) at 1.5 waves/SIMD for a
// latency-chained direct-global kernel. 128x64 tiles -> 768 blocks = exactly
// 3/CU balanced, 3 waves/SIMD (2x TLP).
__global__ __launch_bounds__(256, 3) void gemm_ep(
    const u16* __restrict__ A, const u16* __restrict__ BT,
    const float* __restrict__ bias, void* __restrict__ Cout, int Ntot)
{
    const int tid = threadIdx.x;
    const int wave = tid >> 6, lane = tid & 63;
    const int ln15 = lane & 15, quad = lane >> 4;
    const int m0 = blockIdx.x * 128 + (wave & 1) * 64;
    const int n0 = blockIdx.y * 64 + (wave >> 1) * 32;

    const f32x4 zero = {0.f, 0.f, 0.f, 0.f};
    f32x4 acc[4][2];
    #pragma unroll
    for (int i = 0; i < 4; ++i)
        #pragma unroll
        for (int j = 0; j < 2; ++j) acc[i][j] = zero;

    #pragma unroll
    for (int k0 = 0; k0 < 256; k0 += 32) {
        const int koff = k0 + quad * 8;
        short8 a[4], b[2];
        #pragma unroll
        for (int i = 0; i < 4; ++i)
            a[i] = *(const short8*)(A + (size_t)(m0 + i * 16 + ln15) * 256 + koff);
        #pragma unroll
        for (int j = 0; j < 2; ++j)
            b[j] = *(const short8*)(BT + (size_t)(n0 + j * 16 + ln15) * 256 + koff);
        #pragma unroll
        for (int i = 0; i < 4; ++i)
            #pragma unroll
            for (int j = 0; j < 2; ++j)
                acc[i][j] = mfma16(a[i], b[j], acc[i][j]);
    }

    #pragma unroll
    for (int i = 0; i < 4; ++i) {
        const int r = m0 + i * 16 + quad * 4;
        #pragma unroll
        for (int j = 0; j < 2; ++j) {
            const int c = n0 + j * 16 + ln15;
            const float bv = bias[c];
            #pragma unroll
            for (int rg = 0; rg < 4; ++rg) {
                const size_t idx = (size_t)(r + rg) * Ntot + c;
                ((u16*)Cout)[idx] = f2b(acc[i][j][rg] + bv);
            }
        }
    }
}

// -------- thin MFMA GEMM body, block=64x64, wave=32x32 (Ntot=256) -----------
// mode 1: bf16 C = sigmoid(A@B+bias)  (used by the gate path in rope kernel)
__device__ __forceinline__ void gemm_thin_body(
    int bx, int by, int tid,
    const u16* __restrict__ A, const u16* __restrict__ BT,
    const float* __restrict__ bias, void* __restrict__ Cout,
    const float* __restrict__ xin, const u16* __restrict__ gate,
    int mode)
{
    const int wave = tid >> 6, lane = tid & 63;
    const int ln15 = lane & 15, quad = lane >> 4;
    const int m0 = bx * 64 + (wave & 1) * 32;
    const int n0 = by * 64 + (wave >> 1) * 32;

    const f32x4 zero = {0.f, 0.f, 0.f, 0.f};
    f32x4 acc[2][2];
    #pragma unroll
    for (int i = 0; i < 2; ++i)
        #pragma unroll
        for (int j = 0; j < 2; ++j) acc[i][j] = zero;

    #pragma unroll
    for (int k0 = 0; k0 < 256; k0 += 32) {
        const int koff = k0 + quad * 8;
        short8 a[2], b[2];
        #pragma unroll
        for (int i = 0; i < 2; ++i)
            a[i] = *(const short8*)(A + (size_t)(m0 + i * 16 + ln15) * 256 + koff);
        #pragma unroll
        for (int j = 0; j < 2; ++j)
            b[j] = *(const short8*)(BT + (size_t)(n0 + j * 16 + ln15) * 256 + koff);
        #pragma unroll
        for (int i = 0; i < 2; ++i)
            #pragma unroll
            for (int j = 0; j < 2; ++j)
                acc[i][j] = mfma16(a[i], b[j], acc[i][j]);
    }

    #pragma unroll
    for (int i = 0; i < 2; ++i) {
        const int r = m0 + i * 16 + quad * 4;
        #pragma unroll
        for (int j = 0; j < 2; ++j) {
            const int c = n0 + j * 16 + ln15;
            const float bv = bias[c];
            #pragma unroll
            for (int rg = 0; rg < 4; ++rg) {
                const size_t idx = (size_t)(r + rg) * 256 + c;
                float v = acc[i][j][rg] + bv;
                if (mode == 1) {
                    ((u16*)Cout)[idx] = f2b(1.0f / (1.0f + __expf(-v)));
                } else {
                    ((float*)Cout)[idx] = xin[idx] + b2f(gate[idx]) * v;
                }
            }
        }
    }
}

// -------- out-projection GEMM: block=64x32 (4 waves x 16x32) ----------------
// f32 out = x + gate * (A@B + bias). Old gemm_thin grid was 512 blocks =
// 2 waves/SIMD; 16x32-per-wave gives 1024 blocks = 4/CU balanced, 4 waves/SIMD.
__global__ __launch_bounds__(256, 4) void gemm_out(
    const u16* __restrict__ A, const u16* __restrict__ BT,
    const float* __restrict__ bias, float* __restrict__ out,
    const float* __restrict__ xin, const u16* __restrict__ gate)
{
    const int tid = threadIdx.x;
    const int wave = tid >> 6, lane = tid & 63;
    const int ln15 = lane & 15, quad = lane >> 4;
    const int m0 = blockIdx.x * 64 + wave * 16;
    const int n0 = blockIdx.y * 32;

    const f32x4 zero = {0.f, 0.f, 0.f, 0.f};
    f32x4 acc[2] = {zero, zero};

    #pragma unroll
    for (int k0 = 0; k0 < 256; k0 += 32) {
        const int koff = k0 + quad * 8;
        const short8 a  = *(const short8*)(A + (size_t)(m0 + ln15) * 256 + koff);
        const short8 b0 = *(const short8*)(BT + (size_t)(n0 + ln15) * 256 + koff);
        const short8 b1 = *(const short8*)(BT + (size_t)(n0 + 16 + ln15) * 256 + koff);
        acc[0] = mfma16(a, b0, acc[0]);
        acc[1] = mfma16(a, b1, acc[1]);
    }

    const int r = m0 + quad * 4;
    #pragma unroll
    for (int j = 0; j < 2; ++j) {
        const int c = n0 + j * 16 + ln15;
        const float bv = bias[c];
        #pragma unroll
        for (int rg = 0; rg < 4; ++rg) {
            const size_t idx = (size_t)(r + rg) * 256 + c;
            out[idx] = xin[idx] + b2f(gate[idx]) * (acc[j][rg] + bv);
        }
    }
}

// -------- fused: zc-RMSNorm (blocks 0..2047) + weight transpose (2048..3071)
__global__ __launch_bounds__(256) void norm_transw_k(
    const float* __restrict__ x, const float* __restrict__ g, u16* __restrict__ h,
    const float* __restrict__ wqkv, const float* __restrict__ wout,
    const float* __restrict__ wgate,
    u16* __restrict__ wqkvT, u16* __restrict__ woutT, u16* __restrict__ wgateT)
{
    if (blockIdx.x < 2048) {
        const int wave = threadIdx.x >> 6, lane = threadIdx.x & 63;
        const int t = blockIdx.x * 4 + wave;
        const float4 u = *(const float4*)(x + (size_t)t * D_ + lane * 4);
        float s  = u.x + u.y + u.z + u.w;
        float s2 = u.x * u.x + u.y * u.y + u.z * u.z + u.w * u.w;
        #pragma unroll
        for (int m = 1; m < 64; m <<= 1) {
            s  += __shfl_xor(s, m);
            s2 += __shfl_xor(s2, m);
        }
        float mean = s * (1.0f / D_);
        float var  = s2 * (1.0f / D_) - mean * mean;
        float rinv = rsqrtf(var + 1e-8f);
        const float4 gv = *(const float4*)(g + lane * 4);
        uint2 o;
        o.x = pkbf((u.x - mean) * rinv * gv.x, (u.y - mean) * rinv * gv.y);
        o.y = pkbf((u.z - mean) * rinv * gv.z, (u.w - mean) * rinv * gv.w);
        *(uint2*)(h + (size_t)t * D_ + lane * 4) = o;
    } else {
        int idx = (blockIdx.x - 2048) * 256 + threadIdx.x;
        if (idx < 768 * 256) {
            int nn = idx >> 8, kk = idx & 255;
            wqkvT[idx] = f2b(wqkv[kk * 768 + nn]);
        }
        idx -= 768 * 256;
        if (idx >= 0 && idx < 256 * 256) {
            int nn = idx >> 8, kk = idx & 255;
            woutT[idx]  = f2b(wout[kk * 256 + nn]);
            wgateT[idx] = f2b(wgate[kk * 256 + nn]);
        }
    }
}

// -------- fused: RoPE x4 (0..1023) + V-transpose (1024..1535)
//          + gate GEMM thin (1536..2047)
#define QSCALE 0.18033688f   // 0.125 * log2(e)
__global__ __launch_bounds__(256) void rope_vt_gate_k(
    const u16* __restrict__ qkv, const float* __restrict__ freqs,
    u16* __restrict__ Q, u16* __restrict__ K, u16* __restrict__ VT,
    const u16* __restrict__ h, const u16* __restrict__ wgateT,
    const float* __restrict__ b_gate, u16* __restrict__ gatb)
{
    __shared__ __align__(16) u16 tile[64 * 65];
    const int blk = blockIdx.x;
    if (blk < 1024) {
        const int idx = blk * 256 + threadIdx.x;   // [0, 8192*32)
        const int t = idx >> 5, rem = idx & 31;
        const int hh = rem >> 3, s8 = rem & 7;
        const int b = t >> 11, n = t & 2047;

        const float4 f0 = *(const float4*)(freqs + (size_t)n * 64 + s8 * 8);
        const float4 f1 = *(const float4*)(freqs + (size_t)n * 64 + s8 * 8 + 4);

        const u16* qp = qkv + (size_t)t * 768 + hh * 64 + s8 * 8;
        const uint4 qv = *(const uint4*)qp;
        const uint4 kv = *(const uint4*)(qp + 256);

        const size_t off = ((size_t)(b * H_ + hh) * N_ + n) * DH_ + s8 * 8;
        uint4 qo, ko;
        {
            float q0 = b2f((u16)(qv.x & 0xffff)), q1 = b2f((u16)(qv.x >> 16));
            float k0 = b2f((u16)(kv.x & 0xffff)), k1 = b2f((u16)(kv.x >> 16));
            qo.x = pkbf((q0 * f0.x - q1 * f0.y) * QSCALE, (q0 * f0.y + q1 * f0.x) * QSCALE);
            ko.x = pkbf(k0 * f0.x - k1 * f0.y, k0 * f0.y + k1 * f0.x);
        }
        {
            float q0 = b2f((u16)(qv.y & 0xffff)), q1 = b2f((u16)(qv.y >> 16));
            float k0 = b2f((u16)(kv.y & 0xffff)), k1 = b2f((u16)(kv.y >> 16));
            qo.y = pkbf((q0 * f0.z - q1 * f0.w) * QSCALE, (q0 * f0.w + q1 * f0.z) * QSCALE);
            ko.y = pkbf(k0 * f0.z - k1 * f0.w, k0 * f0.w + k1 * f0.z);
        }
        {
            float q0 = b2f((u16)(qv.z & 0xffff)), q1 = b2f((u16)(qv.z >> 16));
            float k0 = b2f((u16)(kv.z & 0xffff)), k1 = b2f((u16)(kv.z >> 16));
            qo.z = pkbf((q0 * f1.x - q1 * f1.y) * QSCALE, (q0 * f1.y + q1 * f1.x) * QSCALE);
            ko.z = pkbf(k0 * f1.x - k1 * f1.y, k0 * f1.y + k1 * f1.x);
        }
        {
            float q0 = b2f((u16)(qv.w & 0xffff)), q1 = b2f((u16)(qv.w >> 16));
            float k0 = b2f((u16)(kv.w & 0xffff)), k1 = b2f((u16)(kv.w >> 16));
            qo.w = pkbf((q0 * f1.z - q1 * f1.w) * QSCALE, (q0 * f1.w + q1 * f1.z) * QSCALE);
            ko.w = pkbf(k0 * f1.z - k1 * f1.w, k0 * f1.w + k1 * f1.z);
        }
        *(uint4*)(Q + off) = qo;
        *(uint4*)(K + off) = ko;
    } else if (blk < 1536) {
        const int id2 = blk - 1024;
        const int bh = id2 & 15;
        const int n0 = (id2 >> 4) * 64;
        const int b = bh >> 2, hh = bh & 3;
        #pragma unroll
        for (int rep = 0; rep < 16; ++rep) {
            int idx = rep * 256 + threadIdx.x;
            int nl = idx >> 6, dh = idx & 63;
            tile[dh * 65 + nl] = qkv[(size_t)(b * N_ + n0 + nl) * 768 + 512 + hh * 64 + dh];
        }
        __syncthreads();
        #pragma unroll
        for (int rep = 0; rep < 16; ++rep) {
            int idx = rep * 256 + threadIdx.x;
            int dh = idx >> 6, nl = idx & 63;
            VT[((size_t)bh * 64 + dh) * N_ + n0 + nl] = tile[dh * 65 + nl];
        }
    } else {
        const int id3 = blk - 1536;            // [0,512): thin gate GEMM
        gemm_thin_body(id3 & 127, id3 >> 7, threadIdx.x, h, wgateT, b_gate,
                       (void*)gatb, (const float*)nullptr, (const u16*)nullptr, 1);
    }
}

// -------- flash attention, split-K x2: block = 128 q (8 waves) x 1024 keys --
// 8-wave blocks (shared K/V staging for 128 q) + 2-way key split: grid 512,
// 2 blocks/CU x 8 waves = 16 waves/CU. Unnormalized partial O (f32) + lv;
// combine_k merges. T2 XOR swizzle on Ks/Vs (round-3).
__global__ __launch_bounds__(512, 4) void attn_k(
    const u16* __restrict__ Q, const u16* __restrict__ K,
    const u16* __restrict__ VT, float* __restrict__ Op,
    float* __restrict__ lvp)
{
    __shared__ __align__(16) u16 Ks[2][64][64];
    __shared__ __align__(16) u16 Vs[2][64][64];
    __shared__ __align__(16) u16 Pb[8][16 * 88];
    const int tid = threadIdx.x;
    const int wave = tid >> 6, lane = tid & 63;
    const int ln15 = lane & 15, quad = lane >> 4;
    const int id = blockIdx.x;
    // XCD swizzle: id&7 -> fixed bh pair per XCD; half+qb vary within XCD
    const int bh   = ((id & 7) << 1) | ((id >> 3) & 1);
    const int half = (id >> 4) & 1;
    const int q0   = (id >> 5) * 128 + wave * 16;
    const int kt0  = half * 1024;

    const u16* Qh = Q + (size_t)bh * N_ * DH_;
    const u16* Kh = K + (size_t)bh * N_ * DH_;
    const u16* Vh = VT + (size_t)bh * DH_ * N_;

    const short8 bq0 = *(const short8*)(Qh + (size_t)(q0 + ln15) * DH_ + quad * 8);
    const short8 bq1 = *(const short8*)(Qh + (size_t)(q0 + ln15) * DH_ + 32 + quad * 8);

    const f32x4 zero = {0.f, 0.f, 0.f, 0.f};
    f32x4 o[4];
    #pragma unroll
    for (int j = 0; j < 4; ++j) o[j] = zero;
    float lv = 0.f;
    u16* Pw = Pb[wave];

    // staging: 512 threads, 1 uint4 K + 1 uint4 V each
    const int srow = tid >> 3, sq8 = tid & 7;
    const int wc = (sq8 * 8) ^ ((srow & 7) << 3);          // swizzled write col
    const int swl = (ln15 & 7) << 3;                       // swizzled read col
    const int rc0 = (quad * 8) ^ swl;
    const int rc1 = (quad * 8 + 32) ^ swl;

    {
        uint4 k0 = *(const uint4*)(Kh + (size_t)(kt0 + srow) * DH_ + sq8 * 8);
        uint4 v0 = *(const uint4*)(Vh + (size_t)srow * N_ + kt0 + sq8 * 8);
        *(uint4*)&Ks[0][srow][wc] = k0;
        *(uint4*)&Vs[0][srow][wc] = v0;
    }
    __syncthreads();

    int p = 0;
    for (int c = 0; c < 16; ++c) {
        const int ktn = kt0 + (c + 1) * 64;
        uint4 k0, v0;
        const bool more = (c + 1 < 16);
        if (more) {
            k0 = *(const uint4*)(Kh + (size_t)(ktn + srow) * DH_ + sq8 * 8);
            v0 = *(const uint4*)(Vh + (size_t)srow * N_ + ktn + sq8 * 8);
        }

        f32x4 st[4];
        #pragma unroll
        for (int c4 = 0; c4 < 4; ++c4) {
            short8 ka0 = *(const short8*)&Ks[p][c4 * 16 + ln15][rc0];
            short8 ka1 = *(const short8*)&Ks[p][c4 * 16 + ln15][rc1];
            st[c4] = mfma16(ka0, bq0, zero);
            st[c4] = mfma16(ka1, bq1, st[c4]);
        }
        f32x4 pr[4];
        float rs = 0.f;
        #pragma unroll
        for (int c4 = 0; c4 < 4; ++c4) {
            #pragma unroll
            for (int r = 0; r < 4; ++r) {
                pr[c4][r] = exp2f(st[c4][r]);
                rs += pr[c4][r];
            }
        }
        lv += rs;
        #pragma unroll
        for (int c4 = 0; c4 < 4; ++c4) {
            uint2 w;
            w.x = pkbf(pr[c4][0], pr[c4][1]);
            w.y = pkbf(pr[c4][2], pr[c4][3]);
            *(uint2*)(Pw + ln15 * 88 + c4 * 16 + quad * 4) = w;
        }
        asm volatile("s_waitcnt lgkmcnt(0)" ::: "memory");
        const short8 bp0 = *(const short8*)(Pw + ln15 * 88 + quad * 8);
        const short8 bp1 = *(const short8*)(Pw + ln15 * 88 + 32 + quad * 8);
        #pragma unroll
        for (int j = 0; j < 4; ++j) {
            short8 va0 = *(const short8*)&Vs[p][j * 16 + ln15][rc0];
            short8 va1 = *(const short8*)&Vs[p][j * 16 + ln15][rc1];
            o[j] = mfma16(va0, bp0, o[j]);
            o[j] = mfma16(va1, bp1, o[j]);
        }

        if (more) {
            *(uint4*)&Ks[p ^ 1][srow][wc] = k0;
            *(uint4*)&Vs[p ^ 1][srow][wc] = v0;
        }
        __syncthreads();
        p ^= 1;
    }

    lv += __shfl_xor(lv, 16);
    lv += __shfl_xor(lv, 32);
    const size_t rowo = ((size_t)(half * 16 + bh) * N_ + q0 + ln15) * DH_;
    #pragma unroll
    for (int j = 0; j < 4; ++j) {
        float4 w4 = {o[j][0], o[j][1], o[j][2], o[j][3]};
        *(float4*)(Op + rowo + j * 16 + quad * 4) = w4;
    }
    if (quad == 0) lvp[(size_t)(half * 16 + bh) * N_ + q0 + ln15] = lv;
}

// -------- combine: yt = bf16( (O0+O1) / (lv0+lv1) ), [16 bh][2048 q][64 dh]
__global__ __launch_bounds__(256) void combine_k(
    const float* __restrict__ Op, const float* __restrict__ lvp,
    u16* __restrict__ yt)
{
    const int t = blockIdx.x * 256 + threadIdx.x;   // [0, 262144)
    const int dh0 = (t & 7) * 8;
    const int q   = (t >> 3) & 2047;
    const int bh  = t >> 14;
    const size_t o0 = ((size_t)bh * N_ + q) * DH_ + dh0;
    const size_t o1 = o0 + (size_t)16 * N_ * DH_;
    const float4 a0 = *(const float4*)(Op + o0);
    const float4 a1 = *(const float4*)(Op + o0 + 4);
    const float4 c0 = *(const float4*)(Op + o1);
    const float4 c1 = *(const float4*)(Op + o1 + 4);
    const float rl = 1.0f / (lvp[(size_t)bh * N_ + q] + lvp[(size_t)(16 + bh) * N_ + q]);
    uint4 w;
    w.x = pkbf((a0.x + c0.x) * rl, (a0.y + c0.y) * rl);
    w.y = pkbf((a0.z + c0.z) * rl, (a0.w + c0.w) * rl);
    w.z = pkbf((a1.x + c1.x) * rl, (a1.y + c1.y) * rl);
    w.w = pkbf((a1.z + c1.z) * rl, (a1.w + c1.w) * rl);
    const int b = bh >> 2, h = bh & 3;
    *(uint4*)(yt + ((size_t)b * N_ + q) * D_ + h * 64 + dh0) = w;
}

extern "C" void kernel_launch(void* const* d_in, const int* in_sizes, int n_in,
                              void* d_out, int out_size, void* d_ws, size_t ws_size,
                              hipStream_t stream) {
    const float* x      = (const float*)d_in[0];
    const float* freqs  = (const float*)d_in[1];
    const float* g      = (const float*)d_in[2];
    const float* w_qkv  = (const float*)d_in[3];
    const float* b_qkv  = (const float*)d_in[4];
    const float* w_out  = (const float*)d_in[5];
    const float* b_out  = (const float*)d_in[6];
    const float* w_gate = (const float*)d_in[7];
    const float* b_gate = (const float*)d_in[8];
    float* out = (float*)d_out;          // f32 output

    char* ws = (char*)d_ws;
    size_t off = 0;
    auto carve = [&](size_t nelem) -> u16* {
        u16* p = (u16*)(ws + off);
        off += ((nelem * 2 + 255) / 256) * 256;
        return p;
    };
    u16* h      = carve((size_t)BN_ * D_);       // bf16 (4 MB @ 0)
    u16* qkv    = carve((size_t)BN_ * 768);      // bf16 (12 MB @ 4 MB)
    u16* Qb     = carve((size_t)BN_ * D_);       // [B,H,N,DH]
    u16* Kb     = carve((size_t)BN_ * D_);
    u16* VT     = carve((size_t)BN_ * D_);       // [B,H,DH,N]
    u16* gatb   = carve((size_t)BN_ * D_);
    u16* wqkvT  = carve((size_t)768 * 256);
    u16* woutT  = carve((size_t)256 * 256);
    u16* wgateT = carve((size_t)256 * 256);
    // aliases (lifetime-checked):
    //  Op (16 MB f32 partial O) = h+qkv region; both dead after rope_vt_gate_k
    //  lvp (256 KB f32)         = wqkvT region; dead after gemm_ep
    //  yt (4 MB bf16)           = Qb region; dead after attn_k
    float* Op  = (float*)ws;
    float* lvp = (float*)wqkvT;
    u16*   yt  = Qb;

    hipLaunchKernelGGL(norm_transw_k, dim3(3072), dim3(256), 0, stream,
                       x, g, h, w_qkv, w_out, w_gate, wqkvT, woutT, wgateT);
    hipLaunchKernelGGL(gemm_ep, dim3(BN_ / 128, 12), dim3(256), 0, stream,
                       h, wqkvT, b_qkv, (void*)qkv, 768);
    hipLaunchKernelGGL(rope_vt_gate_k, dim3(2048), dim3(256), 0, stream,
                       qkv, freqs, Qb, Kb, VT, h, wgateT, b_gate, gatb);
    hipLaunchKernelGGL(attn_k, dim3(512), dim3(512), 0, stream,
                       Qb, Kb, VT, Op, lvp);
    hipLaunchKernelGGL(combine_k, dim3(1024), dim3(256), 0, stream,
                       Op, lvp, yt);
    hipLaunchKernelGGL(gemm_out, dim3(128, 8), dim3(256), 0, stream,
                       yt, woutT, b_out, out, x, gatb);
}

// Round 6
// 166.757 us; speedup vs baseline: 1.0047x; 1.0047x over previous
//
#include <hip/hip_runtime.h>

typedef unsigned short u16;
typedef unsigned int u32;
typedef short short8 __attribute__((ext_vector_type(8)));
typedef float f32x4 __attribute__((ext_vector_type(4)));
typedef float f32x16 __attribute__((ext_vector_type(16)));

#define B_ 4
#define N_ 2048
#define D_ 256
#define H_ 4
#define DH_ 64
#define BN_ 8192

__device__ inline float b2f(u16 u) {
    union { u32 i; float f; } v; v.i = ((u32)u) << 16; return v.f;
}
// round-half-up bf16: 2 VALU ops
__device__ inline u16 f2b(float f) {
    union { float f; u32 i; } v; v.f = f;
    return (u16)((v.i + 0x8000u) >> 16);
}
// pack two f32 -> bf16 pair (lo=a, hi=b) in 3 VALU via v_perm_b32
__device__ inline u32 pkbf(float a, float b) {
    union { float f; u32 i; } ua, ub; ua.f = a; ub.f = b;
    return __builtin_amdgcn_perm(ub.i + 0x8000u, ua.i + 0x8000u, 0x07060302u);
}
__device__ inline f32x4 mfma16(short8 a, short8 b, f32x4 c) {
    return __builtin_amdgcn_mfma_f32_16x16x32_bf16(a, b, c, 0, 0, 0);
}
__device__ inline f32x16 mfma32(short8 a, short8 b, f32x16 c) {
    return __builtin_amdgcn_mfma_f32_32x32x16_bf16(a, b, c, 0, 0, 0);
}

// -------- MFMA GEMM body, block=128x128, wave=64x64 (qkv) -------------------
__device__ __forceinline__ void gemm_body(
    int bx, int by, int tid,
    const u16* __restrict__ A, const u16* __restrict__ BT,
    const float* __restrict__ bias, void* __restrict__ Cout,
    int Ntot)
{
    const int wave = tid >> 6, lane = tid & 63;
    const int ln15 = lane & 15, quad = lane >> 4;
    const int m0 = bx * 128 + (wave & 1) * 64;
    const int n0 = by * 128 + (wave >> 1) * 64;

    const f32x4 zero = {0.f, 0.f, 0.f, 0.f};
    f32x4 acc[4][4];
    #pragma unroll
    for (int i = 0; i < 4; ++i)
        #pragma unroll
        for (int j = 0; j < 4; ++j) acc[i][j] = zero;

    #pragma unroll
    for (int k0 = 0; k0 < 256; k0 += 32) {
        const int koff = k0 + quad * 8;
        short8 a[4], b[4];
        #pragma unroll
        for (int i = 0; i < 4; ++i)
            a[i] = *(const short8*)(A + (size_t)(m0 + i * 16 + ln15) * 256 + koff);
        #pragma unroll
        for (int j = 0; j < 4; ++j)
            b[j] = *(const short8*)(BT + (size_t)(n0 + j * 16 + ln15) * 256 + koff);
        #pragma unroll
        for (int i = 0; i < 4; ++i)
            #pragma unroll
            for (int j = 0; j < 4; ++j)
                acc[i][j] = mfma16(a[i], b[j], acc[i][j]);
    }

    #pragma unroll
    for (int i = 0; i < 4; ++i) {
        const int r = m0 + i * 16 + quad * 4;
        #pragma unroll
        for (int j = 0; j < 4; ++j) {
            const int c = n0 + j * 16 + ln15;
            const float bv = bias[c];
            #pragma unroll
            for (int rg = 0; rg < 4; ++rg) {
                const size_t idx = (size_t)(r + rg) * Ntot + c;
                ((u16*)Cout)[idx] = f2b(acc[i][j][rg] + bv);
            }
        }
    }
}

// -------- thin MFMA GEMM body, block=64x64, wave=32x32 (Ntot=256) -----------
// mode 1: bf16 C = sigmoid(A@B+bias)   mode 2: f32 C = x + gate*(A@B+bias)
__device__ __forceinline__ void gemm_thin_body(
    int bx, int by, int tid,
    const u16* __restrict__ A, const u16* __restrict__ BT,
    const float* __restrict__ bias, void* __restrict__ Cout,
    const float* __restrict__ xin, const u16* __restrict__ gate,
    int mode)
{
    const int wave = tid >> 6, lane = tid & 63;
    const int ln15 = lane & 15, quad = lane >> 4;
    const int m0 = bx * 64 + (wave & 1) * 32;
    const int n0 = by * 64 + (wave >> 1) * 32;

    const f32x4 zero = {0.f, 0.f, 0.f, 0.f};
    f32x4 acc[2][2];
    #pragma unroll
    for (int i = 0; i < 2; ++i)
        #pragma unroll
        for (int j = 0; j < 2; ++j) acc[i][j] = zero;

    #pragma unroll
    for (int k0 = 0; k0 < 256; k0 += 32) {
        const int koff = k0 + quad * 8;
        short8 a[2], b[2];
        #pragma unroll
        for (int i = 0; i < 2; ++i)
            a[i] = *(const short8*)(A + (size_t)(m0 + i * 16 + ln15) * 256 + koff);
        #pragma unroll
        for (int j = 0; j < 2; ++j)
            b[j] = *(const short8*)(BT + (size_t)(n0 + j * 16 + ln15) * 256 + koff);
        #pragma unroll
        for (int i = 0; i < 2; ++i)
            #pragma unroll
            for (int j = 0; j < 2; ++j)
                acc[i][j] = mfma16(a[i], b[j], acc[i][j]);
    }

    #pragma unroll
    for (int i = 0; i < 2; ++i) {
        const int r = m0 + i * 16 + quad * 4;
        #pragma unroll
        for (int j = 0; j < 2; ++j) {
            const int c = n0 + j * 16 + ln15;
            const float bv = bias[c];
            #pragma unroll
            for (int rg = 0; rg < 4; ++rg) {
                const size_t idx = (size_t)(r + rg) * 256 + c;
                float v = acc[i][j][rg] + bv;
                if (mode == 1) {
                    ((u16*)Cout)[idx] = f2b(1.0f / (1.0f + __expf(-v)));
                } else {
                    ((float*)Cout)[idx] = xin[idx] + b2f(gate[idx]) * v;
                }
            }
        }
    }
}

__global__ __launch_bounds__(256) void gemm_ep(
    const u16* __restrict__ A, const u16* __restrict__ BT,
    const float* __restrict__ bias, void* __restrict__ Cout, int Ntot)
{
    gemm_body(blockIdx.x, blockIdx.y, threadIdx.x, A, BT, bias, Cout, Ntot);
}

__global__ __launch_bounds__(256) void gemm_thin(
    const u16* __restrict__ A, const u16* __restrict__ BT,
    const float* __restrict__ bias, void* __restrict__ Cout,
    const float* __restrict__ xin, const u16* __restrict__ gate, int mode)
{
    gemm_thin_body(blockIdx.x, blockIdx.y, threadIdx.x, A, BT, bias, Cout,
                   xin, gate, mode);
}

// -------- fused: zc-RMSNorm (blocks 0..2047) + weight transpose (2048..3071)
__global__ __launch_bounds__(256) void norm_transw_k(
    const float* __restrict__ x, const float* __restrict__ g, u16* __restrict__ h,
    const float* __restrict__ wqkv, const float* __restrict__ wout,
    const float* __restrict__ wgate,
    u16* __restrict__ wqkvT, u16* __restrict__ woutT, u16* __restrict__ wgateT)
{
    if (blockIdx.x < 2048) {
        const int wave = threadIdx.x >> 6, lane = threadIdx.x & 63;
        const int t = blockIdx.x * 4 + wave;
        const float4 u = *(const float4*)(x + (size_t)t * D_ + lane * 4);
        float s  = u.x + u.y + u.z + u.w;
        float s2 = u.x * u.x + u.y * u.y + u.z * u.z + u.w * u.w;
        #pragma unroll
        for (int m = 1; m < 64; m <<= 1) {
            s  += __shfl_xor(s, m);
            s2 += __shfl_xor(s2, m);
        }
        float mean = s * (1.0f / D_);
        float var  = s2 * (1.0f / D_) - mean * mean;
        float rinv = rsqrtf(var + 1e-8f);
        const float4 gv = *(const float4*)(g + lane * 4);
        uint2 o;
        o.x = pkbf((u.x - mean) * rinv * gv.x, (u.y - mean) * rinv * gv.y);
        o.y = pkbf((u.z - mean) * rinv * gv.z, (u.w - mean) * rinv * gv.w);
        *(uint2*)(h + (size_t)t * D_ + lane * 4) = o;
    } else {
        int idx = (blockIdx.x - 2048) * 256 + threadIdx.x;
        if (idx < 768 * 256) {
            int nn = idx >> 8, kk = idx & 255;
            wqkvT[idx] = f2b(wqkv[kk * 768 + nn]);
        }
        idx -= 768 * 256;
        if (idx >= 0 && idx < 256 * 256) {
            int nn = idx >> 8, kk = idx & 255;
            woutT[idx]  = f2b(wout[kk * 256 + nn]);
            wgateT[idx] = f2b(wgate[kk * 256 + nn]);
        }
    }
}

// -------- fused: RoPE x4 (0..1023) + V-transpose (1024..1535)
//          + gate GEMM thin (1536..2047)
#define QSCALE 0.18033688f   // 0.125 * log2(e)
__global__ __launch_bounds__(256) void rope_vt_gate_k(
    const u16* __restrict__ qkv, const float* __restrict__ freqs,
    u16* __restrict__ Q, u16* __restrict__ K, u16* __restrict__ VT,
    const u16* __restrict__ h, const u16* __restrict__ wgateT,
    const float* __restrict__ b_gate, u16* __restrict__ gatb)
{
    __shared__ __align__(16) u16 tile[64 * 65];
    const int blk = blockIdx.x;
    if (blk < 1024) {
        const int idx = blk * 256 + threadIdx.x;   // [0, 8192*32)
        const int t = idx >> 5, rem = idx & 31;
        const int hh = rem >> 3, s8 = rem & 7;
        const int b = t >> 11, n = t & 2047;

        const float4 f0 = *(const float4*)(freqs + (size_t)n * 64 + s8 * 8);
        const float4 f1 = *(const float4*)(freqs + (size_t)n * 64 + s8 * 8 + 4);

        const u16* qp = qkv + (size_t)t * 768 + hh * 64 + s8 * 8;
        const uint4 qv = *(const uint4*)qp;
        const uint4 kv = *(const uint4*)(qp + 256);

        const size_t off = ((size_t)(b * H_ + hh) * N_ + n) * DH_ + s8 * 8;
        uint4 qo, ko;
        {
            float q0 = b2f((u16)(qv.x & 0xffff)), q1 = b2f((u16)(qv.x >> 16));
            float k0 = b2f((u16)(kv.x & 0xffff)), k1 = b2f((u16)(kv.x >> 16));
            qo.x = pkbf((q0 * f0.x - q1 * f0.y) * QSCALE, (q0 * f0.y + q1 * f0.x) * QSCALE);
            ko.x = pkbf(k0 * f0.x - k1 * f0.y, k0 * f0.y + k1 * f0.x);
        }
        {
            float q0 = b2f((u16)(qv.y & 0xffff)), q1 = b2f((u16)(qv.y >> 16));
            float k0 = b2f((u16)(kv.y & 0xffff)), k1 = b2f((u16)(kv.y >> 16));
            qo.y = pkbf((q0 * f0.z - q1 * f0.w) * QSCALE, (q0 * f0.w + q1 * f0.z) * QSCALE);
            ko.y = pkbf(k0 * f0.z - k1 * f0.w, k0 * f0.w + k1 * f0.z);
        }
        {
            float q0 = b2f((u16)(qv.z & 0xffff)), q1 = b2f((u16)(qv.z >> 16));
            float k0 = b2f((u16)(kv.z & 0xffff)), k1 = b2f((u16)(kv.z >> 16));
            qo.z = pkbf((q0 * f1.x - q1 * f1.y) * QSCALE, (q0 * f1.y + q1 * f1.x) * QSCALE);
            ko.z = pkbf(k0 * f1.x - k1 * f1.y, k0 * f1.y + k1 * f1.x);
        }
        {
            float q0 = b2f((u16)(qv.w & 0xffff)), q1 = b2f((u16)(qv.w >> 16));
            float k0 = b2f((u16)(kv.w & 0xffff)), k1 = b2f((u16)(kv.w >> 16));
            qo.w = pkbf((q0 * f1.z - q1 * f1.w) * QSCALE, (q0 * f1.w + q1 * f1.z) * QSCALE);
            ko.w = pkbf(k0 * f1.z - k1 * f1.w, k0 * f1.w + k1 * f1.z);
        }
        *(uint4*)(Q + off) = qo;
        *(uint4*)(K + off) = ko;
    } else if (blk < 1536) {
        const int id2 = blk - 1024;
        const int bh = id2 & 15;
        const int n0 = (id2 >> 4) * 64;
        const int b = bh >> 2, hh = bh & 3;
        #pragma unroll
        for (int rep = 0; rep < 16; ++rep) {
            int idx = rep * 256 + threadIdx.x;
            int nl = idx >> 6, dh = idx & 63;
            tile[dh * 65 + nl] = qkv[(size_t)(b * N_ + n0 + nl) * 768 + 512 + hh * 64 + dh];
        }
        __syncthreads();
        #pragma unroll
        for (int rep = 0; rep < 16; ++rep) {
            int idx = rep * 256 + threadIdx.x;
            int dh = idx >> 6, nl = idx & 63;
            VT[((size_t)bh * 64 + dh) * N_ + n0 + nl] = tile[dh * 65 + nl];
        }
    } else {
        const int id3 = blk - 1536;            // [0,512): thin gate GEMM
        gemm_thin_body(id3 & 127, id3 >> 7, threadIdx.x, h, wgateT, b_gate,
                       (void*)gatb, (const float*)nullptr, (const u16*)nullptr, 1);
    }
}

// -------- flash attention, split-K x2, 32x32 MFMA, in-register softmax ------
// Round-5 theory: the P LDS round-trip (ds_write -> lgkmcnt(0) -> ds_read)
// was on the serial critical path every iteration. T12 (guide 5.5) removes it:
// with 32x32 MFMA, lane holds P column q=lane&31, keys in C-rows
// (reg&3)+8*(reg>>2)+4*hi. cvt_pk pairs (s,s+1) + v_permlane32_swap_b32 maps
// C regs directly onto the PV B-operand (keys 16kc+{0..7|8..15} by lane half):
// 16 cvt_pk + 8 swaps per 64-key tile, zero LDS, zero lgkmcnt. Wave = 32 q,
// 4 waves = 128 q/block, grid 512 = 2 independent blocks/CU (slip vs each
// other). K/V staging + XOR swizzle + split-2 unchanged; Pb gone (LDS 32KB).
__global__ __launch_bounds__(256, 2) void attn_k(
    const u16* __restrict__ Q, const u16* __restrict__ K,
    const u16* __restrict__ VT, float* __restrict__ Op,
    float* __restrict__ lvp)
{
    __shared__ __align__(16) u16 Ks[2][64][64];
    __shared__ __align__(16) u16 Vs[2][64][64];
    const int tid = threadIdx.x;
    const int wave = tid >> 6, lane = tid & 63;
    const int l31 = lane & 31, hi = lane >> 5;
    const int id = blockIdx.x;
    // XCD swizzle: id&7 -> fixed bh pair per XCD
    const int bh   = ((id & 7) << 1) | ((id >> 3) & 1);
    const int half = (id >> 4) & 1;
    const int q0   = (id >> 5) * 128 + wave * 32;
    const int kt0  = half * 1024;

    const u16* Qh = Q + (size_t)bh * N_ * DH_;
    const u16* Kh = K + (size_t)bh * N_ * DH_;
    const u16* Vh = VT + (size_t)bh * DH_ * N_;

    // Q as B-operand: n = q = l31, k = kc*16 + hi*8 + j
    short8 bq[4];
    #pragma unroll
    for (int kc = 0; kc < 4; ++kc)
        bq[kc] = *(const short8*)(Qh + (size_t)(q0 + l31) * DH_ + kc * 16 + hi * 8);

    f32x16 o0, o1;   // O^T[dh 0..31][q], O^T[dh 32..63][q]
    #pragma unroll
    for (int i = 0; i < 16; ++i) { o0[i] = 0.f; o1[i] = 0.f; }
    float lv = 0.f;

    // staging: 256 threads, 2 uint4 K + 2 uint4 V each
    const int srow = tid >> 2, sq4 = tid & 3;
    const int sw = srow & 7;
    const int wg0 = ((sq4) ^ sw) * 8;          // swizzled write cols (u16)
    const int wg1 = ((sq4 + 4) ^ sw) * 8;
    const int rsw = l31 & 7;                   // read-row swizzle phase

    {
        uint4 k0 = *(const uint4*)(Kh + (size_t)(kt0 + srow) * DH_ + sq4 * 8);
        uint4 k1 = *(const uint4*)(Kh + (size_t)(kt0 + srow) * DH_ + (sq4 + 4) * 8);
        uint4 v0 = *(const uint4*)(Vh + (size_t)srow * N_ + kt0 + sq4 * 8);
        uint4 v1 = *(const uint4*)(Vh + (size_t)srow * N_ + kt0 + (sq4 + 4) * 8);
        *(uint4*)&Ks[0][srow][wg0] = k0;
        *(uint4*)&Ks[0][srow][wg1] = k1;
        *(uint4*)&Vs[0][srow][wg0] = v0;
        *(uint4*)&Vs[0][srow][wg1] = v1;
    }
    __syncthreads();

    int p = 0;
    for (int c = 0; c < 16; ++c) {
        const bool more = (c + 1 < 16);
        uint4 k0, k1, v0, v1;
        if (more) {
            const int ktn = kt0 + (c + 1) * 64;
            k0 = *(const uint4*)(Kh + (size_t)(ktn + srow) * DH_ + sq4 * 8);
            k1 = *(const uint4*)(Kh + (size_t)(ktn + srow) * DH_ + (sq4 + 4) * 8);
            v0 = *(const uint4*)(Vh + (size_t)srow * N_ + ktn + sq4 * 8);
            v1 = *(const uint4*)(Vh + (size_t)srow * N_ + ktn + (sq4 + 4) * 8);
        }

        // QK^T: S^T[key][q] per 32-key group g; A = K rows, B = Q
        f32x16 st0, st1;
        #pragma unroll
        for (int i = 0; i < 16; ++i) { st0[i] = 0.f; st1[i] = 0.f; }
        #pragma unroll
        for (int kc = 0; kc < 4; ++kc) {
            const int gran = ((2 * kc + hi) ^ rsw) * 8;
            short8 ka0 = *(const short8*)&Ks[p][l31][gran];
            short8 ka1 = *(const short8*)&Ks[p][32 + l31][gran];
            st0 = mfma32(ka0, bq[kc], st0);
            st1 = mfma32(ka1, bq[kc], st1);
        }

        // softmax numerator (no running max; |s| bounded, QSCALE pre-applied)
        // + pack P into PV B-fragments via cvt_pk + permlane32_swap (T12)
        short8 pb[4];
        #pragma unroll
        for (int g = 0; g < 2; ++g) {
            float pr[16];
            #pragma unroll
            for (int r = 0; r < 16; ++r) {
                pr[r] = exp2f(g ? st1[r] : st0[r]);
                lv += pr[r];
            }
            #pragma unroll
            for (int kc2 = 0; kc2 < 2; ++kc2) {
                u32 X0, X1, Y0, Y1;
                asm("v_cvt_pk_bf16_f32 %0, %1, %2" : "=v"(X0) : "v"(pr[8*kc2+0]), "v"(pr[8*kc2+1]));
                asm("v_cvt_pk_bf16_f32 %0, %1, %2" : "=v"(X1) : "v"(pr[8*kc2+2]), "v"(pr[8*kc2+3]));
                asm("v_cvt_pk_bf16_f32 %0, %1, %2" : "=v"(Y0) : "v"(pr[8*kc2+4]), "v"(pr[8*kc2+5]));
                asm("v_cvt_pk_bf16_f32 %0, %1, %2" : "=v"(Y1) : "v"(pr[8*kc2+6]), "v"(pr[8*kc2+7]));
                asm("v_permlane32_swap_b32 %0, %1" : "+v"(X0), "+v"(Y0));
                asm("v_permlane32_swap_b32 %0, %1" : "+v"(X1), "+v"(Y1));
                union { u32 u[4]; short8 s; } bf;
                bf.u[0] = X0; bf.u[1] = X1; bf.u[2] = Y0; bf.u[3] = Y1;
                pb[g * 2 + kc2] = bf.s;
            }
        }

        // PV: O^T[dh][q] += V^T[dh][key] * P^T[key][q]; A = Vs rows (dh)
        #pragma unroll
        for (int kc = 0; kc < 4; ++kc) {
            const int gran = ((2 * kc + hi) ^ rsw) * 8;
            short8 va0 = *(const short8*)&Vs[p][l31][gran];
            short8 va1 = *(const short8*)&Vs[p][32 + l31][gran];
            o0 = mfma32(va0, pb[kc], o0);
            o1 = mfma32(va1, pb[kc], o1);
        }

        if (more) {
            *(uint4*)&Ks[p ^ 1][srow][wg0] = k0;
            *(uint4*)&Ks[p ^ 1][srow][wg1] = k1;
            *(uint4*)&Vs[p ^ 1][srow][wg0] = v0;
            *(uint4*)&Vs[p ^ 1][srow][wg1] = v1;
        }
        __syncthreads();
        p ^= 1;
    }

    lv += __shfl_xor(lv, 32);
    const size_t rowo = ((size_t)(half * 16 + bh) * N_ + q0 + l31) * DH_;
    #pragma unroll
    for (int go = 0; go < 2; ++go) {
        #pragma unroll
        for (int rq = 0; rq < 4; ++rq) {
            float4 w4;
            if (go == 0) {
                w4.x = o0[rq*4+0]; w4.y = o0[rq*4+1]; w4.z = o0[rq*4+2]; w4.w = o0[rq*4+3];
            } else {
                w4.x = o1[rq*4+0]; w4.y = o1[rq*4+1]; w4.z = o1[rq*4+2]; w4.w = o1[rq*4+3];
            }
            *(float4*)(Op + rowo + go * 32 + 8 * rq + 4 * hi) = w4;
        }
    }
    if (hi == 0) lvp[(size_t)(half * 16 + bh) * N_ + q0 + l31] = lv;
}

// -------- combine: yt = bf16( (O0+O1) / (lv0+lv1) ), [16 bh][2048 q][64 dh]
__global__ __launch_bounds__(256) void combine_k(
    const float* __restrict__ Op, const float* __restrict__ lvp,
    u16* __restrict__ yt)
{
    const int t = blockIdx.x * 256 + threadIdx.x;   // [0, 262144)
    const int dh0 = (t & 7) * 8;
    const int q   = (t >> 3) & 2047;
    const int bh  = t >> 14;
    const size_t o0 = ((size_t)bh * N_ + q) * DH_ + dh0;
    const size_t o1 = o0 + (size_t)16 * N_ * DH_;
    const float4 a0 = *(const float4*)(Op + o0);
    const float4 a1 = *(const float4*)(Op + o0 + 4);
    const float4 c0 = *(const float4*)(Op + o1);
    const float4 c1 = *(const float4*)(Op + o1 + 4);
    const float rl = 1.0f / (lvp[(size_t)bh * N_ + q] + lvp[(size_t)(16 + bh) * N_ + q]);
    uint4 w;
    w.x = pkbf((a0.x + c0.x) * rl, (a0.y + c0.y) * rl);
    w.y = pkbf((a0.z + c0.z) * rl, (a0.w + c0.w) * rl);
    w.z = pkbf((a1.x + c1.x) * rl, (a1.y + c1.y) * rl);
    w.w = pkbf((a1.z + c1.z) * rl, (a1.w + c1.w) * rl);
    const int b = bh >> 2, h = bh & 3;
    *(uint4*)(yt + ((size_t)b * N_ + q) * D_ + h * 64 + dh0) = w;
}

extern "C" void kernel_launch(void* const* d_in, const int* in_sizes, int n_in,
                              void* d_out, int out_size, void* d_ws, size_t ws_size,
                              hipStream_t stream) {
    const float* x      = (const float*)d_in[0];
    const float* freqs  = (const float*)d_in[1];
    const float* g      = (const float*)d_in[2];
    const float* w_qkv  = (const float*)d_in[3];
    const float* b_qkv  = (const float*)d_in[4];
    const float* w_out  = (const float*)d_in[5];
    const float* b_out  = (const float*)d_in[6];
    const float* w_gate = (const float*)d_in[7];
    const float* b_gate = (const float*)d_in[8];
    float* out = (float*)d_out;          // f32 output

    char* ws = (char*)d_ws;
    size_t off = 0;
    auto carve = [&](size_t nelem) -> u16* {
        u16* p = (u16*)(ws + off);
        off += ((nelem * 2 + 255) / 256) * 256;
        return p;
    };
    u16* h      = carve((size_t)BN_ * D_);       // bf16 (4 MB @ 0)
    u16* qkv    = carve((size_t)BN_ * 768);      // bf16 (12 MB @ 4 MB)
    u16* Qb     = carve((size_t)BN_ * D_);       // [B,H,N,DH]
    u16* Kb     = carve((size_t)BN_ * D_);
    u16* VT     = carve((size_t)BN_ * D_);       // [B,H,DH,N]
    u16* gatb   = carve((size_t)BN_ * D_);
    u16* wqkvT  = carve((size_t)768 * 256);
    u16* woutT  = carve((size_t)256 * 256);
    u16* wgateT = carve((size_t)256 * 256);
    // aliases (lifetime-checked):
    //  Op (16 MB f32 partial O) = h+qkv region; both dead after rope_vt_gate_k
    //  lvp (256 KB f32)         = wqkvT region; dead after gemm_ep
    //  yt (4 MB bf16)           = Qb region; dead after attn_k
    float* Op  = (float*)ws;
    float* lvp = (float*)wqkvT;
    u16*   yt  = Qb;

    hipLaunchKernelGGL(norm_transw_k, dim3(3072), dim3(256), 0, stream,
                       x, g, h, w_qkv, w_out, w_gate, wqkvT, woutT, wgateT);
    hipLaunchKernelGGL(gemm_ep, dim3(BN_ / 128, 6), dim3(256), 0, stream,
                       h, wqkvT, b_qkv, (void*)qkv, 768);
    hipLaunchKernelGGL(rope_vt_gate_k, dim3(2048), dim3(256), 0, stream,
                       qkv, freqs, Qb, Kb, VT, h, wgateT, b_gate, gatb);
    hipLaunchKernelGGL(attn_k, dim3(512), dim3(256), 0, stream,
                       Qb, Kb, VT, Op, lvp);
    hipLaunchKernelGGL(combine_k, dim3(1024), dim3(256), 0, stream,
                       Op, lvp, yt);
    hipLaunchKernelGGL(gemm_thin, dim3(128, 4), dim3(256), 0, stream,
                       yt, woutT, b_out, (void*)out, x, gatb, 2);
}

// Round 7
// 162.216 us; speedup vs baseline: 1.0328x; 1.0280x over previous
//
#include <hip/hip_runtime.h>

typedef unsigned short u16;
typedef unsigned int u32;
typedef short short8 __attribute__((ext_vector_type(8)));
typedef float f32x4 __attribute__((ext_vector_type(4)));
typedef float f32x16 __attribute__((ext_vector_type(16)));

#define B_ 4
#define N_ 2048
#define D_ 256
#define H_ 4
#define DH_ 64
#define BN_ 8192

__device__ inline float b2f(u16 u) {
    union { u32 i; float f; } v; v.i = ((u32)u) << 16; return v.f;
}
// round-half-up bf16: 2 VALU ops
__device__ inline u16 f2b(float f) {
    union { float f; u32 i; } v; v.f = f;
    return (u16)((v.i + 0x8000u) >> 16);
}
// pack two f32 -> bf16 pair (lo=a, hi=b) in 3 VALU via v_perm_b32
__device__ inline u32 pkbf(float a, float b) {
    union { float f; u32 i; } ua, ub; ua.f = a; ub.f = b;
    return __builtin_amdgcn_perm(ub.i + 0x8000u, ua.i + 0x8000u, 0x07060302u);
}
__device__ inline f32x4 mfma16(short8 a, short8 b, f32x4 c) {
    return __builtin_amdgcn_mfma_f32_16x16x32_bf16(a, b, c, 0, 0, 0);
}
__device__ inline f32x16 mfma32(short8 a, short8 b, f32x16 c) {
    return __builtin_amdgcn_mfma_f32_32x32x16_bf16(a, b, c, 0, 0, 0);
}

// -------- MFMA GEMM body, block=128x128, wave=64x64 (qkv) -------------------
__device__ __forceinline__ void gemm_body(
    int bx, int by, int tid,
    const u16* __restrict__ A, const u16* __restrict__ BT,
    const float* __restrict__ bias, void* __restrict__ Cout,
    int Ntot)
{
    const int wave = tid >> 6, lane = tid & 63;
    const int ln15 = lane & 15, quad = lane >> 4;
    const int m0 = bx * 128 + (wave & 1) * 64;
    const int n0 = by * 128 + (wave >> 1) * 64;

    const f32x4 zero = {0.f, 0.f, 0.f, 0.f};
    f32x4 acc[4][4];
    #pragma unroll
    for (int i = 0; i < 4; ++i)
        #pragma unroll
        for (int j = 0; j < 4; ++j) acc[i][j] = zero;

    #pragma unroll
    for (int k0 = 0; k0 < 256; k0 += 32) {
        const int koff = k0 + quad * 8;
        short8 a[4], b[4];
        #pragma unroll
        for (int i = 0; i < 4; ++i)
            a[i] = *(const short8*)(A + (size_t)(m0 + i * 16 + ln15) * 256 + koff);
        #pragma unroll
        for (int j = 0; j < 4; ++j)
            b[j] = *(const short8*)(BT + (size_t)(n0 + j * 16 + ln15) * 256 + koff);
        #pragma unroll
        for (int i = 0; i < 4; ++i)
            #pragma unroll
            for (int j = 0; j < 4; ++j)
                acc[i][j] = mfma16(a[i], b[j], acc[i][j]);
    }

    #pragma unroll
    for (int i = 0; i < 4; ++i) {
        const int r = m0 + i * 16 + quad * 4;
        #pragma unroll
        for (int j = 0; j < 4; ++j) {
            const int c = n0 + j * 16 + ln15;
            const float bv = bias[c];
            #pragma unroll
            for (int rg = 0; rg < 4; ++rg) {
                const size_t idx = (size_t)(r + rg) * Ntot + c;
                ((u16*)Cout)[idx] = f2b(acc[i][j][rg] + bv);
            }
        }
    }
}

// -------- thin MFMA GEMM body, block=64x64, wave=32x32 (Ntot=256) -----------
// mode 1: bf16 C = sigmoid(A@B+bias)   mode 2: f32 C = x + gate*(A@B+bias)
__device__ __forceinline__ void gemm_thin_body(
    int bx, int by, int tid,
    const u16* __restrict__ A, const u16* __restrict__ BT,
    const float* __restrict__ bias, void* __restrict__ Cout,
    const float* __restrict__ xin, const u16* __restrict__ gate,
    int mode)
{
    const int wave = tid >> 6, lane = tid & 63;
    const int ln15 = lane & 15, quad = lane >> 4;
    const int m0 = bx * 64 + (wave & 1) * 32;
    const int n0 = by * 64 + (wave >> 1) * 32;

    const f32x4 zero = {0.f, 0.f, 0.f, 0.f};
    f32x4 acc[2][2];
    #pragma unroll
    for (int i = 0; i < 2; ++i)
        #pragma unroll
        for (int j = 0; j < 2; ++j) acc[i][j] = zero;

    #pragma unroll
    for (int k0 = 0; k0 < 256; k0 += 32) {
        const int koff = k0 + quad * 8;
        short8 a[2], b[2];
        #pragma unroll
        for (int i = 0; i < 2; ++i)
            a[i] = *(const short8*)(A + (size_t)(m0 + i * 16 + ln15) * 256 + koff);
        #pragma unroll
        for (int j = 0; j < 2; ++j)
            b[j] = *(const short8*)(BT + (size_t)(n0 + j * 16 + ln15) * 256 + koff);
        #pragma unroll
        for (int i = 0; i < 2; ++i)
            #pragma unroll
            for (int j = 0; j < 2; ++j)
                acc[i][j] = mfma16(a[i], b[j], acc[i][j]);
    }

    #pragma unroll
    for (int i = 0; i < 2; ++i) {
        const int r = m0 + i * 16 + quad * 4;
        #pragma unroll
        for (int j = 0; j < 2; ++j) {
            const int c = n0 + j * 16 + ln15;
            const float bv = bias[c];
            #pragma unroll
            for (int rg = 0; rg < 4; ++rg) {
                const size_t idx = (size_t)(r + rg) * 256 + c;
                float v = acc[i][j][rg] + bv;
                if (mode == 1) {
                    ((u16*)Cout)[idx] = f2b(1.0f / (1.0f + __expf(-v)));
                } else {
                    ((float*)Cout)[idx] = xin[idx] + b2f(gate[idx]) * v;
                }
            }
        }
    }
}

__global__ __launch_bounds__(256) void gemm_ep(
    const u16* __restrict__ A, const u16* __restrict__ BT,
    const float* __restrict__ bias, void* __restrict__ Cout, int Ntot)
{
    gemm_body(blockIdx.x, blockIdx.y, threadIdx.x, A, BT, bias, Cout, Ntot);
}

__global__ __launch_bounds__(256) void gemm_thin(
    const u16* __restrict__ A, const u16* __restrict__ BT,
    const float* __restrict__ bias, void* __restrict__ Cout,
    const float* __restrict__ xin, const u16* __restrict__ gate, int mode)
{
    gemm_thin_body(blockIdx.x, blockIdx.y, threadIdx.x, A, BT, bias, Cout,
                   xin, gate, mode);
}

// -------- fused: zc-RMSNorm (blocks 0..2047) + weight transpose (2048..3071)
__global__ __launch_bounds__(256) void norm_transw_k(
    const float* __restrict__ x, const float* __restrict__ g, u16* __restrict__ h,
    const float* __restrict__ wqkv, const float* __restrict__ wout,
    const float* __restrict__ wgate,
    u16* __restrict__ wqkvT, u16* __restrict__ woutT, u16* __restrict__ wgateT)
{
    if (blockIdx.x < 2048) {
        const int wave = threadIdx.x >> 6, lane = threadIdx.x & 63;
        const int t = blockIdx.x * 4 + wave;
        const float4 u = *(const float4*)(x + (size_t)t * D_ + lane * 4);
        float s  = u.x + u.y + u.z + u.w;
        float s2 = u.x * u.x + u.y * u.y + u.z * u.z + u.w * u.w;
        #pragma unroll
        for (int m = 1; m < 64; m <<= 1) {
            s  += __shfl_xor(s, m);
            s2 += __shfl_xor(s2, m);
        }
        float mean = s * (1.0f / D_);
        float var  = s2 * (1.0f / D_) - mean * mean;
        float rinv = rsqrtf(var + 1e-8f);
        const float4 gv = *(const float4*)(g + lane * 4);
        uint2 o;
        o.x = pkbf((u.x - mean) * rinv * gv.x, (u.y - mean) * rinv * gv.y);
        o.y = pkbf((u.z - mean) * rinv * gv.z, (u.w - mean) * rinv * gv.w);
        *(uint2*)(h + (size_t)t * D_ + lane * 4) = o;
    } else {
        int idx = (blockIdx.x - 2048) * 256 + threadIdx.x;
        if (idx < 768 * 256) {
            int nn = idx >> 8, kk = idx & 255;
            wqkvT[idx] = f2b(wqkv[kk * 768 + nn]);
        }
        idx -= 768 * 256;
        if (idx >= 0 && idx < 256 * 256) {
            int nn = idx >> 8, kk = idx & 255;
            woutT[idx]  = f2b(wout[kk * 256 + nn]);
            wgateT[idx] = f2b(wgate[kk * 256 + nn]);
        }
    }
}

// -------- fused: RoPE x4 (0..1023) + V-transpose (1024..1535)
//          + gate GEMM thin (1536..2047)
#define QSCALE 0.18033688f   // 0.125 * log2(e)
__global__ __launch_bounds__(256) void rope_vt_gate_k(
    const u16* __restrict__ qkv, const float* __restrict__ freqs,
    u16* __restrict__ Q, u16* __restrict__ K, u16* __restrict__ VT,
    const u16* __restrict__ h, const u16* __restrict__ wgateT,
    const float* __restrict__ b_gate, u16* __restrict__ gatb)
{
    __shared__ __align__(16) u16 tile[64 * 65];
    const int blk = blockIdx.x;
    if (blk < 1024) {
        const int idx = blk * 256 + threadIdx.x;   // [0, 8192*32)
        const int t = idx >> 5, rem = idx & 31;
        const int hh = rem >> 3, s8 = rem & 7;
        const int b = t >> 11, n = t & 2047;

        const float4 f0 = *(const float4*)(freqs + (size_t)n * 64 + s8 * 8);
        const float4 f1 = *(const float4*)(freqs + (size_t)n * 64 + s8 * 8 + 4);

        const u16* qp = qkv + (size_t)t * 768 + hh * 64 + s8 * 8;
        const uint4 qv = *(const uint4*)qp;
        const uint4 kv = *(const uint4*)(qp + 256);

        const size_t off = ((size_t)(b * H_ + hh) * N_ + n) * DH_ + s8 * 8;
        uint4 qo, ko;
        {
            float q0 = b2f((u16)(qv.x & 0xffff)), q1 = b2f((u16)(qv.x >> 16));
            float k0 = b2f((u16)(kv.x & 0xffff)), k1 = b2f((u16)(kv.x >> 16));
            qo.x = pkbf((q0 * f0.x - q1 * f0.y) * QSCALE, (q0 * f0.y + q1 * f0.x) * QSCALE);
            ko.x = pkbf(k0 * f0.x - k1 * f0.y, k0 * f0.y + k1 * f0.x);
        }
        {
            float q0 = b2f((u16)(qv.y & 0xffff)), q1 = b2f((u16)(qv.y >> 16));
            float k0 = b2f((u16)(kv.y & 0xffff)), k1 = b2f((u16)(kv.y >> 16));
            qo.y = pkbf((q0 * f0.z - q1 * f0.w) * QSCALE, (q0 * f0.w + q1 * f0.z) * QSCALE);
            ko.y = pkbf(k0 * f0.z - k1 * f0.w, k0 * f0.w + k1 * f0.z);
        }
        {
            float q0 = b2f((u16)(qv.z & 0xffff)), q1 = b2f((u16)(qv.z >> 16));
            float k0 = b2f((u16)(kv.z & 0xffff)), k1 = b2f((u16)(kv.z >> 16));
            qo.z = pkbf((q0 * f1.x - q1 * f1.y) * QSCALE, (q0 * f1.y + q1 * f1.x) * QSCALE);
            ko.z = pkbf(k0 * f1.x - k1 * f1.y, k0 * f1.y + k1 * f1.x);
        }
        {
            float q0 = b2f((u16)(qv.w & 0xffff)), q1 = b2f((u16)(qv.w >> 16));
            float k0 = b2f((u16)(kv.w & 0xffff)), k1 = b2f((u16)(kv.w >> 16));
            qo.w = pkbf((q0 * f1.z - q1 * f1.w) * QSCALE, (q0 * f1.w + q1 * f1.z) * QSCALE);
            ko.w = pkbf(k0 * f1.z - k1 * f1.w, k0 * f1.w + k1 * f1.z);
        }
        *(uint4*)(Q + off) = qo;
        *(uint4*)(K + off) = ko;
    } else if (blk < 1536) {
        const int id2 = blk - 1024;
        const int bh = id2 & 15;
        const int n0 = (id2 >> 4) * 64;
        const int b = bh >> 2, hh = bh & 3;
        #pragma unroll
        for (int rep = 0; rep < 16; ++rep) {
            int idx = rep * 256 + threadIdx.x;
            int nl = idx >> 6, dh = idx & 63;
            tile[dh * 65 + nl] = qkv[(size_t)(b * N_ + n0 + nl) * 768 + 512 + hh * 64 + dh];
        }
        __syncthreads();
        #pragma unroll
        for (int rep = 0; rep < 16; ++rep) {
            int idx = rep * 256 + threadIdx.x;
            int dh = idx >> 6, nl = idx & 63;
            VT[((size_t)bh * 64 + dh) * N_ + n0 + nl] = tile[dh * 65 + nl];
        }
    } else {
        const int id3 = blk - 1536;            // [0,512): thin gate GEMM
        gemm_thin_body(id3 & 127, id3 >> 7, threadIdx.x, h, wgateT, b_gate,
                       (void*)gatb, (const float*)nullptr, (const u16*)nullptr, 1);
    }
}

// -------- flash attention, split-K x4, 32x32 MFMA, in-register softmax ------
// Round-6 post-mortem: T12 (in-register softmax) doubled per-wave efficiency
// but at 8 waves/CU it was TLP-neutralized (same 40us as R4's 16-wave split-2).
// This version stacks both: grid 1024 = 4 blocks/CU exact x 4 waves = 16
// waves/CU (4/SIMD, VGPR cap 128 via __launch_bounds__(256,4)). To fit 128
// VGPR the tile body is GROUP-SEQUENTIAL: process the two 32-key halves one
// after the other (QK -> exp-in-place -> pack -> PV per half), peak live
// state ~110 regs and a shorter exp chain. 4 partials; combine reads 4.
__global__ __launch_bounds__(256, 4) void attn_k(
    const u16* __restrict__ Q, const u16* __restrict__ K,
    const u16* __restrict__ VT, float* __restrict__ Op,
    float* __restrict__ lvp)
{
    __shared__ __align__(16) u16 Ks[2][64][64];
    __shared__ __align__(16) u16 Vs[2][64][64];
    const int tid = threadIdx.x;
    const int wave = tid >> 6, lane = tid & 63;
    const int l31 = lane & 31, hi = lane >> 5;
    const int id = blockIdx.x;
    // XCD swizzle: id&7 -> fixed bh pair per XCD
    const int bh   = ((id & 7) << 1) | ((id >> 3) & 1);
    const int quar = (id >> 4) & 3;
    const int q0   = (id >> 6) * 128 + wave * 32;
    const int kt0  = quar * 512;

    const u16* Qh = Q + (size_t)bh * N_ * DH_;
    const u16* Kh = K + (size_t)bh * N_ * DH_;
    const u16* Vh = VT + (size_t)bh * DH_ * N_;

    // Q as B-operand: n = q = l31, k = kc*16 + hi*8 + j
    short8 bq[4];
    #pragma unroll
    for (int kc = 0; kc < 4; ++kc)
        bq[kc] = *(const short8*)(Qh + (size_t)(q0 + l31) * DH_ + kc * 16 + hi * 8);

    f32x16 o0, o1;   // O^T[dh 0..31][q], O^T[dh 32..63][q]
    #pragma unroll
    for (int i = 0; i < 16; ++i) { o0[i] = 0.f; o1[i] = 0.f; }
    float lv = 0.f;

    // staging: 256 threads, 2 uint4 K + 2 uint4 V each
    const int srow = tid >> 2, sq4 = tid & 3;
    const int sw = srow & 7;
    const int wg0 = ((sq4) ^ sw) * 8;          // swizzled write cols (u16)
    const int wg1 = ((sq4 + 4) ^ sw) * 8;
    const int rsw = l31 & 7;                   // read-row swizzle phase

    {
        uint4 k0 = *(const uint4*)(Kh + (size_t)(kt0 + srow) * DH_ + sq4 * 8);
        uint4 k1 = *(const uint4*)(Kh + (size_t)(kt0 + srow) * DH_ + (sq4 + 4) * 8);
        uint4 v0 = *(const uint4*)(Vh + (size_t)srow * N_ + kt0 + sq4 * 8);
        uint4 v1 = *(const uint4*)(Vh + (size_t)srow * N_ + kt0 + (sq4 + 4) * 8);
        *(uint4*)&Ks[0][srow][wg0] = k0;
        *(uint4*)&Ks[0][srow][wg1] = k1;
        *(uint4*)&Vs[0][srow][wg0] = v0;
        *(uint4*)&Vs[0][srow][wg1] = v1;
    }
    __syncthreads();

    int p = 0;
    for (int c = 0; c < 8; ++c) {
        const bool more = (c + 1 < 8);
        uint4 k0, k1, v0, v1;
        if (more) {
            const int ktn = kt0 + (c + 1) * 64;
            k0 = *(const uint4*)(Kh + (size_t)(ktn + srow) * DH_ + sq4 * 8);
            k1 = *(const uint4*)(Kh + (size_t)(ktn + srow) * DH_ + (sq4 + 4) * 8);
            v0 = *(const uint4*)(Vh + (size_t)srow * N_ + ktn + sq4 * 8);
            v1 = *(const uint4*)(Vh + (size_t)srow * N_ + ktn + (sq4 + 4) * 8);
        }

        // group-sequential: keys 32g..32g+31 (g = key-row group)
        #pragma unroll
        for (int g = 0; g < 2; ++g) {
            // QK^T: S^T[key][q]; A = K rows (32g + l31), B = Q
            f32x16 st;
            #pragma unroll
            for (int i = 0; i < 16; ++i) st[i] = 0.f;
            #pragma unroll
            for (int kc = 0; kc < 4; ++kc) {
                const int gran = ((2 * kc + hi) ^ rsw) * 8;
                short8 ka = *(const short8*)&Ks[p][g * 32 + l31][gran];
                st = mfma32(ka, bq[kc], st);
            }
            // softmax numerator in place (no running max; QSCALE pre-applied)
            #pragma unroll
            for (int r = 0; r < 16; ++r) {
                st[r] = exp2f(st[r]);
                lv += st[r];
            }
            // pack P into PV B-fragments (T12: cvt_pk + permlane32_swap)
            #pragma unroll
            for (int kc2 = 0; kc2 < 2; ++kc2) {
                u32 X0, X1, Y0, Y1;
                asm("v_cvt_pk_bf16_f32 %0, %1, %2" : "=v"(X0) : "v"(st[8*kc2+0]), "v"(st[8*kc2+1]));
                asm("v_cvt_pk_bf16_f32 %0, %1, %2" : "=v"(X1) : "v"(st[8*kc2+2]), "v"(st[8*kc2+3]));
                asm("v_cvt_pk_bf16_f32 %0, %1, %2" : "=v"(Y0) : "v"(st[8*kc2+4]), "v"(st[8*kc2+5]));
                asm("v_cvt_pk_bf16_f32 %0, %1, %2" : "=v"(Y1) : "v"(st[8*kc2+6]), "v"(st[8*kc2+7]));
                asm("v_permlane32_swap_b32 %0, %1" : "+v"(X0), "+v"(Y0));
                asm("v_permlane32_swap_b32 %0, %1" : "+v"(X1), "+v"(Y1));
                union { u32 u[4]; short8 s; } bf;
                bf.u[0] = X0; bf.u[1] = X1; bf.u[2] = Y0; bf.u[3] = Y1;
                // PV for key-chunk kc = 2g + kc2 (keys 16kc+0..15)
                const int gran = ((2 * (2 * g + kc2) + hi) ^ rsw) * 8;
                short8 va0 = *(const short8*)&Vs[p][l31][gran];
                short8 va1 = *(const short8*)&Vs[p][32 + l31][gran];
                o0 = mfma32(va0, bf.s, o0);
                o1 = mfma32(va1, bf.s, o1);
            }
        }

        if (more) {
            *(uint4*)&Ks[p ^ 1][srow][wg0] = k0;
            *(uint4*)&Ks[p ^ 1][srow][wg1] = k1;
            *(uint4*)&Vs[p ^ 1][srow][wg0] = v0;
            *(uint4*)&Vs[p ^ 1][srow][wg1] = v1;
        }
        __syncthreads();
        p ^= 1;
    }

    lv += __shfl_xor(lv, 32);
    const size_t rowo = ((size_t)(quar * 16 + bh) * N_ + q0 + l31) * DH_;
    #pragma unroll
    for (int go = 0; go < 2; ++go) {
        #pragma unroll
        for (int rq = 0; rq < 4; ++rq) {
            float4 w4;
            if (go == 0) {
                w4.x = o0[rq*4+0]; w4.y = o0[rq*4+1]; w4.z = o0[rq*4+2]; w4.w = o0[rq*4+3];
            } else {
                w4.x = o1[rq*4+0]; w4.y = o1[rq*4+1]; w4.z = o1[rq*4+2]; w4.w = o1[rq*4+3];
            }
            *(float4*)(Op + rowo + go * 32 + 8 * rq + 4 * hi) = w4;
        }
    }
    if (hi == 0) lvp[(size_t)(quar * 16 + bh) * N_ + q0 + l31] = lv;
}

// -------- combine: yt = bf16( sum4(O) / sum4(lv) ), [16 bh][2048 q][64 dh] --
__global__ __launch_bounds__(256) void combine_k(
    const float* __restrict__ Op, const float* __restrict__ lvp,
    u16* __restrict__ yt)
{
    const int t = blockIdx.x * 256 + threadIdx.x;   // [0, 262144)
    const int dh0 = (t & 7) * 8;
    const int q   = (t >> 3) & 2047;
    const int bh  = t >> 14;
    float a[8];
    #pragma unroll
    for (int i = 0; i < 8; ++i) a[i] = 0.f;
    float lsum = 0.f;
    #pragma unroll
    for (int pp = 0; pp < 4; ++pp) {
        const size_t o0 = ((size_t)(pp * 16 + bh) * N_ + q) * DH_ + dh0;
        const float4 u0 = *(const float4*)(Op + o0);
        const float4 u1 = *(const float4*)(Op + o0 + 4);
        a[0] += u0.x; a[1] += u0.y; a[2] += u0.z; a[3] += u0.w;
        a[4] += u1.x; a[5] += u1.y; a[6] += u1.z; a[7] += u1.w;
        lsum += lvp[(size_t)(pp * 16 + bh) * N_ + q];
    }
    const float rl = 1.0f / lsum;
    uint4 w;
    w.x = pkbf(a[0] * rl, a[1] * rl);
    w.y = pkbf(a[2] * rl, a[3] * rl);
    w.z = pkbf(a[4] * rl, a[5] * rl);
    w.w = pkbf(a[6] * rl, a[7] * rl);
    const int b = bh >> 2, h = bh & 3;
    *(uint4*)(yt + ((size_t)b * N_ + q) * D_ + h * 64 + dh0) = w;
}

extern "C" void kernel_launch(void* const* d_in, const int* in_sizes, int n_in,
                              void* d_out, int out_size, void* d_ws, size_t ws_size,
                              hipStream_t stream) {
    const float* x      = (const float*)d_in[0];
    const float* freqs  = (const float*)d_in[1];
    const float* g      = (const float*)d_in[2];
    const float* w_qkv  = (const float*)d_in[3];
    const float* b_qkv  = (const float*)d_in[4];
    const float* w_out  = (const float*)d_in[5];
    const float* b_out  = (const float*)d_in[6];
    const float* w_gate = (const float*)d_in[7];
    const float* b_gate = (const float*)d_in[8];
    float* out = (float*)d_out;          // f32 output

    char* ws = (char*)d_ws;
    size_t off = 0;
    auto carve = [&](size_t nelem) -> u16* {
        u16* p = (u16*)(ws + off);
        off += ((nelem * 2 + 255) / 256) * 256;
        return p;
    };
    u16* h      = carve((size_t)BN_ * D_);       // bf16 (4 MB)
    u16* qkv    = carve((size_t)BN_ * 768);      // bf16 (12 MB)
    u16* Qb     = carve((size_t)BN_ * D_);       // [B,H,N,DH]
    u16* Kb     = carve((size_t)BN_ * D_);
    u16* VT     = carve((size_t)BN_ * D_);       // [B,H,DH,N]
    u16* gatb   = carve((size_t)BN_ * D_);
    u16* wqkvT  = carve((size_t)768 * 256);
    u16* woutT  = carve((size_t)256 * 256);
    u16* wgateT = carve((size_t)256 * 256);
    // split-K x4 partials, carved fresh (workspace >= 268 MB per fill size):
    float* Op  = (float*)carve((size_t)4 * 16 * N_ * DH_ * 2);  // 32 MB f32
    float* lvp = (float*)carve((size_t)4 * 16 * N_ * 2);        // 512 KB f32
    u16*   yt  = Qb;    // dead after attn_k

    hipLaunchKernelGGL(norm_transw_k, dim3(3072), dim3(256), 0, stream,
                       x, g, h, w_qkv, w_out, w_gate, wqkvT, woutT, wgateT);
    hipLaunchKernelGGL(gemm_ep, dim3(BN_ / 128, 6), dim3(256), 0, stream,
                       h, wqkvT, b_qkv, (void*)qkv, 768);
    hipLaunchKernelGGL(rope_vt_gate_k, dim3(2048), dim3(256), 0, stream,
                       qkv, freqs, Qb, Kb, VT, h, wgateT, b_gate, gatb);
    hipLaunchKernelGGL(attn_k, dim3(1024), dim3(256), 0, stream,
                       Qb, Kb, VT, Op, lvp);
    hipLaunchKernelGGL(combine_k, dim3(1024), dim3(256), 0, stream,
                       Op, lvp, yt);
    hipLaunchKernelGGL(gemm_thin, dim3(128, 4), dim3(256), 0, stream,
                       yt, woutT, b_out, (void*)out, x, gatb, 2);
}

// Round 8
// 148.801 us; speedup vs baseline: 1.1259x; 1.0902x over previous
//
#include <hip/hip_runtime.h>

typedef unsigned short u16;
typedef unsigned int u32;
typedef short short8 __attribute__((ext_vector_type(8)));
typedef float f32x4 __attribute__((ext_vector_type(4)));
typedef float f32x16 __attribute__((ext_vector_type(16)));

#define B_ 4
#define N_ 2048
#define D_ 256
#define H_ 4
#define DH_ 64
#define BN_ 8192

__device__ inline float b2f(u16 u) {
    union { u32 i; float f; } v; v.i = ((u32)u) << 16; return v.f;
}
// round-half-up bf16: 2 VALU ops
__device__ inline u16 f2b(float f) {
    union { float f; u32 i; } v; v.f = f;
    return (u16)((v.i + 0x8000u) >> 16);
}
// pack two f32 -> bf16 pair (lo=a, hi=b) in 3 VALU via v_perm_b32
__device__ inline u32 pkbf(float a, float b) {
    union { float f; u32 i; } ua, ub; ua.f = a; ub.f = b;
    return __builtin_amdgcn_perm(ub.i + 0x8000u, ua.i + 0x8000u, 0x07060302u);
}
__device__ inline f32x4 mfma16(short8 a, short8 b, f32x4 c) {
    return __builtin_amdgcn_mfma_f32_16x16x32_bf16(a, b, c, 0, 0, 0);
}
__device__ inline f32x16 mfma32(short8 a, short8 b, f32x16 c) {
    return __builtin_amdgcn_mfma_f32_32x32x16_bf16(a, b, c, 0, 0, 0);
}

#define QSCALE 0.18033688f   // 0.125 * log2(e)

// -------- fused front-end GEMM: C = h @ [wqkv | wgate] (M=8192,N=1024,K=256)
// Round-7 theory: the old pipeline wrote qkv (12 MB), then a separate
// latency-bound pass re-read it (12 MB), applied RoPE/V-transpose/(gate), and
// wrote 16 MB. All that epilogue math is cheap and the GEMM already holds the
// values in registers -> fuse. Column ranges: [0,512) Q,K with in-register
// RoPE (pair exchange = __shfl_xor(v,1); freqs gather; Q scaled by QSCALE),
// [512,768) V stored transposed into VT, [768,1024) sigmoid gate.
// Removes rope_vt_gate_k + the qkv buffer entirely (~24 MB HBM round-trip).
// RoPE now rotates pre-quantization f32 accs (more accurate than before).
// Grid 64x8 = 512 blocks = 2/CU exact.
__global__ __launch_bounds__(256) void gemm_front(
    const u16* __restrict__ A, const u16* __restrict__ BT,   // BT = [1024][256]
    const float* __restrict__ b_qkv, const float* __restrict__ b_gate,
    const float* __restrict__ freqs,
    u16* __restrict__ Qb, u16* __restrict__ Kb,
    u16* __restrict__ VT, u16* __restrict__ gatb)
{
    const int tid = threadIdx.x;
    const int wave = tid >> 6, lane = tid & 63;
    const int ln15 = lane & 15, quad = lane >> 4;
    const int by = blockIdx.y;
    const int m0 = blockIdx.x * 128 + (wave & 1) * 64;
    const int n0 = by * 128 + (wave >> 1) * 64;

    const f32x4 zero = {0.f, 0.f, 0.f, 0.f};
    f32x4 acc[4][4];
    #pragma unroll
    for (int i = 0; i < 4; ++i)
        #pragma unroll
        for (int j = 0; j < 4; ++j) acc[i][j] = zero;

    #pragma unroll
    for (int k0 = 0; k0 < 256; k0 += 32) {
        const int koff = k0 + quad * 8;
        short8 a[4], b[4];
        #pragma unroll
        for (int i = 0; i < 4; ++i)
            a[i] = *(const short8*)(A + (size_t)(m0 + i * 16 + ln15) * 256 + koff);
        #pragma unroll
        for (int j = 0; j < 4; ++j)
            b[j] = *(const short8*)(BT + (size_t)(n0 + j * 16 + ln15) * 256 + koff);
        #pragma unroll
        for (int i = 0; i < 4; ++i)
            #pragma unroll
            for (int j = 0; j < 4; ++j)
                acc[i][j] = mfma16(a[i], b[j], acc[i][j]);
    }

    if (by < 4) {
        // ---- Q,K + RoPE. c<256 -> Q (scaled); else K. Pair = lane^1.
        #pragma unroll
        for (int j = 0; j < 4; ++j) {
            const int c  = n0 + j * 16 + ln15;
            const int hh = (c >> 6) & 3;
            const int dh = c & 63;
            const int d2 = dh >> 1;
            const bool isQ = (c < 256);
            const bool ev  = ((dh & 1) == 0);
            const float bv = b_qkv[c];
            u16* dst = isQ ? Qb : Kb;
            #pragma unroll
            for (int i = 0; i < 4; ++i) {
                const int r = m0 + i * 16 + quad * 4;
                #pragma unroll
                for (int rg = 0; rg < 4; ++rg) {
                    const int t = r + rg;
                    const int n = t & 2047, b = t >> 11;
                    float v = acc[i][j][rg] + bv;
                    float pv = __shfl_xor(v, 1);
                    const float2 cs = *(const float2*)(freqs + (size_t)n * 64 + d2 * 2);
                    float o = ev ? (v * cs.x - pv * cs.y)
                                 : (pv * cs.y + v * cs.x);
                    if (isQ) o *= QSCALE;
                    dst[((size_t)(b * H_ + hh) * N_ + n) * DH_ + dh] = f2b(o);
                }
            }
        }
    } else if (by < 6) {
        // ---- V, written directly transposed: VT[bh][dh][n] (8B per store)
        #pragma unroll
        for (int j = 0; j < 4; ++j) {
            const int c  = n0 + j * 16 + ln15;      // 512..767
            const int hh = (c >> 6) & 3;
            const int dh = c & 63;
            const float bv = b_qkv[c];
            #pragma unroll
            for (int i = 0; i < 4; ++i) {
                const int r = m0 + i * 16 + quad * 4;  // r%4==0, same b for rg 0..3
                const int n = r & 2047, b = r >> 11;
                uint2 w;
                w.x = pkbf(acc[i][j][0] + bv, acc[i][j][1] + bv);
                w.y = pkbf(acc[i][j][2] + bv, acc[i][j][3] + bv);
                *(uint2*)(VT + ((size_t)(b * H_ + hh) * DH_ + dh) * N_ + n) = w;
            }
        }
    } else {
        // ---- gate: sigmoid -> gatb[t][256]
        #pragma unroll
        for (int j = 0; j < 4; ++j) {
            const int c  = n0 + j * 16 + ln15;      // 768..1023
            const int cg = c - 768;
            const float bv = b_gate[cg];
            #pragma unroll
            for (int i = 0; i < 4; ++i) {
                const int r = m0 + i * 16 + quad * 4;
                #pragma unroll
                for (int rg = 0; rg < 4; ++rg) {
                    float v = acc[i][j][rg] + bv;
                    gatb[(size_t)(r + rg) * 256 + cg] = f2b(1.0f / (1.0f + __expf(-v)));
                }
            }
        }
    }
}

// -------- out-projection GEMM, block=64x64, wave=32x32 ----------------------
// f32 out = x + gate * (yt@woutT + bias)
__global__ __launch_bounds__(256) void gemm_thin(
    const u16* __restrict__ A, const u16* __restrict__ BT,
    const float* __restrict__ bias, float* __restrict__ out,
    const float* __restrict__ xin, const u16* __restrict__ gate)
{
    const int tid = threadIdx.x;
    const int wave = tid >> 6, lane = tid & 63;
    const int ln15 = lane & 15, quad = lane >> 4;
    const int m0 = blockIdx.x * 64 + (wave & 1) * 32;
    const int n0 = blockIdx.y * 64 + (wave >> 1) * 32;

    const f32x4 zero = {0.f, 0.f, 0.f, 0.f};
    f32x4 acc[2][2];
    #pragma unroll
    for (int i = 0; i < 2; ++i)
        #pragma unroll
        for (int j = 0; j < 2; ++j) acc[i][j] = zero;

    #pragma unroll
    for (int k0 = 0; k0 < 256; k0 += 32) {
        const int koff = k0 + quad * 8;
        short8 a[2], b[2];
        #pragma unroll
        for (int i = 0; i < 2; ++i)
            a[i] = *(const short8*)(A + (size_t)(m0 + i * 16 + ln15) * 256 + koff);
        #pragma unroll
        for (int j = 0; j < 2; ++j)
            b[j] = *(const short8*)(BT + (size_t)(n0 + j * 16 + ln15) * 256 + koff);
        #pragma unroll
        for (int i = 0; i < 2; ++i)
            #pragma unroll
            for (int j = 0; j < 2; ++j)
                acc[i][j] = mfma16(a[i], b[j], acc[i][j]);
    }

    #pragma unroll
    for (int i = 0; i < 2; ++i) {
        const int r = m0 + i * 16 + quad * 4;
        #pragma unroll
        for (int j = 0; j < 2; ++j) {
            const int c = n0 + j * 16 + ln15;
            const float bv = bias[c];
            #pragma unroll
            for (int rg = 0; rg < 4; ++rg) {
                const size_t idx = (size_t)(r + rg) * 256 + c;
                out[idx] = xin[idx] + b2f(gate[idx]) * (acc[i][j][rg] + bv);
            }
        }
    }
}

// -------- fused: zc-RMSNorm (blocks 0..2047) + weight transpose (2048..3071)
__global__ __launch_bounds__(256) void norm_transw_k(
    const float* __restrict__ x, const float* __restrict__ g, u16* __restrict__ h,
    const float* __restrict__ wqkv, const float* __restrict__ wout,
    const float* __restrict__ wgate,
    u16* __restrict__ wqkvT, u16* __restrict__ woutT, u16* __restrict__ wgateT)
{
    if (blockIdx.x < 2048) {
        const int wave = threadIdx.x >> 6, lane = threadIdx.x & 63;
        const int t = blockIdx.x * 4 + wave;
        const float4 u = *(const float4*)(x + (size_t)t * D_ + lane * 4);
        float s  = u.x + u.y + u.z + u.w;
        float s2 = u.x * u.x + u.y * u.y + u.z * u.z + u.w * u.w;
        #pragma unroll
        for (int m = 1; m < 64; m <<= 1) {
            s  += __shfl_xor(s, m);
            s2 += __shfl_xor(s2, m);
        }
        float mean = s * (1.0f / D_);
        float var  = s2 * (1.0f / D_) - mean * mean;
        float rinv = rsqrtf(var + 1e-8f);
        const float4 gv = *(const float4*)(g + lane * 4);
        uint2 o;
        o.x = pkbf((u.x - mean) * rinv * gv.x, (u.y - mean) * rinv * gv.y);
        o.y = pkbf((u.z - mean) * rinv * gv.z, (u.w - mean) * rinv * gv.w);
        *(uint2*)(h + (size_t)t * D_ + lane * 4) = o;
    } else {
        int idx = (blockIdx.x - 2048) * 256 + threadIdx.x;
        if (idx < 768 * 256) {
            int nn = idx >> 8, kk = idx & 255;
            wqkvT[idx] = f2b(wqkv[kk * 768 + nn]);
        }
        idx -= 768 * 256;
        if (idx >= 0 && idx < 256 * 256) {
            int nn = idx >> 8, kk = idx & 255;
            woutT[idx]  = f2b(wout[kk * 256 + nn]);
            wgateT[idx] = f2b(wgate[kk * 256 + nn]);
        }
    }
}

// -------- flash attention, split-K x4, 32x32 MFMA, in-register softmax ------
// 4 blocks/CU exact x 4 waves = 16 waves/CU; T12 in-register softmax
// (cvt_pk + permlane32_swap), group-sequential halves for VGPR<=128.
__global__ __launch_bounds__(256, 4) void attn_k(
    const u16* __restrict__ Q, const u16* __restrict__ K,
    const u16* __restrict__ VT, float* __restrict__ Op,
    float* __restrict__ lvp)
{
    __shared__ __align__(16) u16 Ks[2][64][64];
    __shared__ __align__(16) u16 Vs[2][64][64];
    const int tid = threadIdx.x;
    const int wave = tid >> 6, lane = tid & 63;
    const int l31 = lane & 31, hi = lane >> 5;
    const int id = blockIdx.x;
    // XCD swizzle: id&7 -> fixed bh pair per XCD
    const int bh   = ((id & 7) << 1) | ((id >> 3) & 1);
    const int quar = (id >> 4) & 3;
    const int q0   = (id >> 6) * 128 + wave * 32;
    const int kt0  = quar * 512;

    const u16* Qh = Q + (size_t)bh * N_ * DH_;
    const u16* Kh = K + (size_t)bh * N_ * DH_;
    const u16* Vh = VT + (size_t)bh * DH_ * N_;

    // Q as B-operand: n = q = l31, k = kc*16 + hi*8 + j
    short8 bq[4];
    #pragma unroll
    for (int kc = 0; kc < 4; ++kc)
        bq[kc] = *(const short8*)(Qh + (size_t)(q0 + l31) * DH_ + kc * 16 + hi * 8);

    f32x16 o0, o1;   // O^T[dh 0..31][q], O^T[dh 32..63][q]
    #pragma unroll
    for (int i = 0; i < 16; ++i) { o0[i] = 0.f; o1[i] = 0.f; }
    float lv = 0.f;

    // staging: 256 threads, 2 uint4 K + 2 uint4 V each
    const int srow = tid >> 2, sq4 = tid & 3;
    const int sw = srow & 7;
    const int wg0 = ((sq4) ^ sw) * 8;          // swizzled write cols (u16)
    const int wg1 = ((sq4 + 4) ^ sw) * 8;
    const int rsw = l31 & 7;                   // read-row swizzle phase

    {
        uint4 k0 = *(const uint4*)(Kh + (size_t)(kt0 + srow) * DH_ + sq4 * 8);
        uint4 k1 = *(const uint4*)(Kh + (size_t)(kt0 + srow) * DH_ + (sq4 + 4) * 8);
        uint4 v0 = *(const uint4*)(Vh + (size_t)srow * N_ + kt0 + sq4 * 8);
        uint4 v1 = *(const uint4*)(Vh + (size_t)srow * N_ + kt0 + (sq4 + 4) * 8);
        *(uint4*)&Ks[0][srow][wg0] = k0;
        *(uint4*)&Ks[0][srow][wg1] = k1;
        *(uint4*)&Vs[0][srow][wg0] = v0;
        *(uint4*)&Vs[0][srow][wg1] = v1;
    }
    __syncthreads();

    int p = 0;
    for (int c = 0; c < 8; ++c) {
        const bool more = (c + 1 < 8);
        uint4 k0, k1, v0, v1;
        if (more) {
            const int ktn = kt0 + (c + 1) * 64;
            k0 = *(const uint4*)(Kh + (size_t)(ktn + srow) * DH_ + sq4 * 8);
            k1 = *(const uint4*)(Kh + (size_t)(ktn + srow) * DH_ + (sq4 + 4) * 8);
            v0 = *(const uint4*)(Vh + (size_t)srow * N_ + ktn + sq4 * 8);
            v1 = *(const uint4*)(Vh + (size_t)srow * N_ + ktn + (sq4 + 4) * 8);
        }

        // group-sequential: keys 32g..32g+31 (g = key-row group)
        #pragma unroll
        for (int g = 0; g < 2; ++g) {
            // QK^T: S^T[key][q]; A = K rows (32g + l31), B = Q
            f32x16 st;
            #pragma unroll
            for (int i = 0; i < 16; ++i) st[i] = 0.f;
            #pragma unroll
            for (int kc = 0; kc < 4; ++kc) {
                const int gran = ((2 * kc + hi) ^ rsw) * 8;
                short8 ka = *(const short8*)&Ks[p][g * 32 + l31][gran];
                st = mfma32(ka, bq[kc], st);
            }
            // softmax numerator in place (no running max; QSCALE pre-applied)
            #pragma unroll
            for (int r = 0; r < 16; ++r) {
                st[r] = exp2f(st[r]);
                lv += st[r];
            }
            // pack P into PV B-fragments (T12: cvt_pk + permlane32_swap)
            #pragma unroll
            for (int kc2 = 0; kc2 < 2; ++kc2) {
                u32 X0, X1, Y0, Y1;
                asm("v_cvt_pk_bf16_f32 %0, %1, %2" : "=v"(X0) : "v"(st[8*kc2+0]), "v"(st[8*kc2+1]));
                asm("v_cvt_pk_bf16_f32 %0, %1, %2" : "=v"(X1) : "v"(st[8*kc2+2]), "v"(st[8*kc2+3]));
                asm("v_cvt_pk_bf16_f32 %0, %1, %2" : "=v"(Y0) : "v"(st[8*kc2+4]), "v"(st[8*kc2+5]));
                asm("v_cvt_pk_bf16_f32 %0, %1, %2" : "=v"(Y1) : "v"(st[8*kc2+6]), "v"(st[8*kc2+7]));
                asm("v_permlane32_swap_b32 %0, %1" : "+v"(X0), "+v"(Y0));
                asm("v_permlane32_swap_b32 %0, %1" : "+v"(X1), "+v"(Y1));
                union { u32 u[4]; short8 s; } bf;
                bf.u[0] = X0; bf.u[1] = X1; bf.u[2] = Y0; bf.u[3] = Y1;
                // PV for key-chunk kc = 2g + kc2 (keys 16kc+0..15)
                const int gran = ((2 * (2 * g + kc2) + hi) ^ rsw) * 8;
                short8 va0 = *(const short8*)&Vs[p][l31][gran];
                short8 va1 = *(const short8*)&Vs[p][32 + l31][gran];
                o0 = mfma32(va0, bf.s, o0);
                o1 = mfma32(va1, bf.s, o1);
            }
        }

        if (more) {
            *(uint4*)&Ks[p ^ 1][srow][wg0] = k0;
            *(uint4*)&Ks[p ^ 1][srow][wg1] = k1;
            *(uint4*)&Vs[p ^ 1][srow][wg0] = v0;
            *(uint4*)&Vs[p ^ 1][srow][wg1] = v1;
        }
        __syncthreads();
        p ^= 1;
    }

    lv += __shfl_xor(lv, 32);
    const size_t rowo = ((size_t)(quar * 16 + bh) * N_ + q0 + l31) * DH_;
    #pragma unroll
    for (int go = 0; go < 2; ++go) {
        #pragma unroll
        for (int rq = 0; rq < 4; ++rq) {
            float4 w4;
            if (go == 0) {
                w4.x = o0[rq*4+0]; w4.y = o0[rq*4+1]; w4.z = o0[rq*4+2]; w4.w = o0[rq*4+3];
            } else {
                w4.x = o1[rq*4+0]; w4.y = o1[rq*4+1]; w4.z = o1[rq*4+2]; w4.w = o1[rq*4+3];
            }
            *(float4*)(Op + rowo + go * 32 + 8 * rq + 4 * hi) = w4;
        }
    }
    if (hi == 0) lvp[(size_t)(quar * 16 + bh) * N_ + q0 + l31] = lv;
}

// -------- combine: yt = bf16( sum4(O) / sum4(lv) ), [16 bh][2048 q][64 dh] --
__global__ __launch_bounds__(256) void combine_k(
    const float* __restrict__ Op, const float* __restrict__ lvp,
    u16* __restrict__ yt)
{
    const int t = blockIdx.x * 256 + threadIdx.x;   // [0, 262144)
    const int dh0 = (t & 7) * 8;
    const int q   = (t >> 3) & 2047;
    const int bh  = t >> 14;
    float a[8];
    #pragma unroll
    for (int i = 0; i < 8; ++i) a[i] = 0.f;
    float lsum = 0.f;
    #pragma unroll
    for (int pp = 0; pp < 4; ++pp) {
        const size_t o0 = ((size_t)(pp * 16 + bh) * N_ + q) * DH_ + dh0;
        const float4 u0 = *(const float4*)(Op + o0);
        const float4 u1 = *(const float4*)(Op + o0 + 4);
        a[0] += u0.x; a[1] += u0.y; a[2] += u0.z; a[3] += u0.w;
        a[4] += u1.x; a[5] += u1.y; a[6] += u1.z; a[7] += u1.w;
        lsum += lvp[(size_t)(pp * 16 + bh) * N_ + q];
    }
    const float rl = 1.0f / lsum;
    uint4 w;
    w.x = pkbf(a[0] * rl, a[1] * rl);
    w.y = pkbf(a[2] * rl, a[3] * rl);
    w.z = pkbf(a[4] * rl, a[5] * rl);
    w.w = pkbf(a[6] * rl, a[7] * rl);
    const int b = bh >> 2, h = bh & 3;
    *(uint4*)(yt + ((size_t)b * N_ + q) * D_ + h * 64 + dh0) = w;
}

extern "C" void kernel_launch(void* const* d_in, const int* in_sizes, int n_in,
                              void* d_out, int out_size, void* d_ws, size_t ws_size,
                              hipStream_t stream) {
    const float* x      = (const float*)d_in[0];
    const float* freqs  = (const float*)d_in[1];
    const float* g      = (const float*)d_in[2];
    const float* w_qkv  = (const float*)d_in[3];
    const float* b_qkv  = (const float*)d_in[4];
    const float* w_out  = (const float*)d_in[5];
    const float* b_out  = (const float*)d_in[6];
    const float* w_gate = (const float*)d_in[7];
    const float* b_gate = (const float*)d_in[8];
    float* out = (float*)d_out;          // f32 output

    char* ws = (char*)d_ws;
    size_t off = 0;
    auto carve = [&](size_t nelem) -> u16* {
        u16* p = (u16*)(ws + off);
        off += ((nelem * 2 + 255) / 256) * 256;
        return p;
    };
    u16* h      = carve((size_t)BN_ * D_);       // bf16 (4 MB)
    u16* Qb     = carve((size_t)BN_ * D_);       // [B,H,N,DH]
    u16* Kb     = carve((size_t)BN_ * D_);
    u16* VT     = carve((size_t)BN_ * D_);       // [B,H,DH,N]
    u16* gatb   = carve((size_t)BN_ * D_);
    // wcatT = [wqkvT (768 rows) | wgateT (256 rows)] contiguous, then woutT
    u16* wqkvT  = carve((size_t)768 * 256);
    u16* wgateT = carve((size_t)256 * 256);      // = wqkvT + 768*256
    u16* woutT  = carve((size_t)256 * 256);
    // split-K x4 partials:
    float* Op  = (float*)carve((size_t)4 * 16 * N_ * DH_ * 2);  // 32 MB f32
    float* lvp = (float*)carve((size_t)4 * 16 * N_ * 2);        // 512 KB f32
    u16*   yt  = Qb;    // dead after attn_k

    hipLaunchKernelGGL(norm_transw_k, dim3(3072), dim3(256), 0, stream,
                       x, g, h, w_qkv, w_out, w_gate, wqkvT, woutT, wgateT);
    hipLaunchKernelGGL(gemm_front, dim3(64, 8), dim3(256), 0, stream,
                       h, wqkvT, b_qkv, b_gate, freqs, Qb, Kb, VT, gatb);
    hipLaunchKernelGGL(attn_k, dim3(1024), dim3(256), 0, stream,
                       Qb, Kb, VT, Op, lvp);
    hipLaunchKernelGGL(combine_k, dim3(1024), dim3(256), 0, stream,
                       Op, lvp, yt);
    hipLaunchKernelGGL(gemm_thin, dim3(128, 4), dim3(256), 0, stream,
                       yt, woutT, b_out, out, x, gatb);
}

// Round 9
// 146.992 us; speedup vs baseline: 1.1398x; 1.0123x over previous
//
#include <hip/hip_runtime.h>

typedef unsigned short u16;
typedef unsigned int u32;
typedef short short8 __attribute__((ext_vector_type(8)));
typedef float f32x4 __attribute__((ext_vector_type(4)));
typedef float f32x16 __attribute__((ext_vector_type(16)));

#define B_ 4
#define N_ 2048
#define D_ 256
#define H_ 4
#define DH_ 64
#define BN_ 8192

__device__ inline float b2f(u16 u) {
    union { u32 i; float f; } v; v.i = ((u32)u) << 16; return v.f;
}
// round-half-up bf16: 2 VALU ops
__device__ inline u16 f2b(float f) {
    union { float f; u32 i; } v; v.f = f;
    return (u16)((v.i + 0x8000u) >> 16);
}
// pack two f32 -> bf16 pair (lo=a, hi=b) in 3 VALU via v_perm_b32
__device__ inline u32 pkbf(float a, float b) {
    union { float f; u32 i; } ua, ub; ua.f = a; ub.f = b;
    return __builtin_amdgcn_perm(ub.i + 0x8000u, ua.i + 0x8000u, 0x07060302u);
}
__device__ inline f32x4 mfma16(short8 a, short8 b, f32x4 c) {
    return __builtin_amdgcn_mfma_f32_16x16x32_bf16(a, b, c, 0, 0, 0);
}
__device__ inline f32x16 mfma32(short8 a, short8 b, f32x16 c) {
    return __builtin_amdgcn_mfma_f32_32x32x16_bf16(a, b, c, 0, 0, 0);
}

#define QSCALE 0.18033688f   // 0.125 * log2(e)

// -------- fused front-end GEMM: C = h @ [wqkv | wgate] (M=8192,N=1024,K=256)
// Column ranges: [0,512) Q,K with in-register RoPE (pair = __shfl_xor(v,1)),
// [512,768) V stored transposed into VT, [768,1024) sigmoid gate.
__global__ __launch_bounds__(256) void gemm_front(
    const u16* __restrict__ A, const u16* __restrict__ BT,   // BT = [1024][256]
    const float* __restrict__ b_qkv, const float* __restrict__ b_gate,
    const float* __restrict__ freqs,
    u16* __restrict__ Qb, u16* __restrict__ Kb,
    u16* __restrict__ VT, u16* __restrict__ gatb)
{
    const int tid = threadIdx.x;
    const int wave = tid >> 6, lane = tid & 63;
    const int ln15 = lane & 15, quad = lane >> 4;
    const int by = blockIdx.y;
    const int m0 = blockIdx.x * 128 + (wave & 1) * 64;
    const int n0 = by * 128 + (wave >> 1) * 64;

    const f32x4 zero = {0.f, 0.f, 0.f, 0.f};
    f32x4 acc[4][4];
    #pragma unroll
    for (int i = 0; i < 4; ++i)
        #pragma unroll
        for (int j = 0; j < 4; ++j) acc[i][j] = zero;

    #pragma unroll
    for (int k0 = 0; k0 < 256; k0 += 32) {
        const int koff = k0 + quad * 8;
        short8 a[4], b[4];
        #pragma unroll
        for (int i = 0; i < 4; ++i)
            a[i] = *(const short8*)(A + (size_t)(m0 + i * 16 + ln15) * 256 + koff);
        #pragma unroll
        for (int j = 0; j < 4; ++j)
            b[j] = *(const short8*)(BT + (size_t)(n0 + j * 16 + ln15) * 256 + koff);
        #pragma unroll
        for (int i = 0; i < 4; ++i)
            #pragma unroll
            for (int j = 0; j < 4; ++j)
                acc[i][j] = mfma16(a[i], b[j], acc[i][j]);
    }

    if (by < 4) {
        // ---- Q,K + RoPE. c<256 -> Q (scaled); else K. Pair = lane^1.
        #pragma unroll
        for (int j = 0; j < 4; ++j) {
            const int c  = n0 + j * 16 + ln15;
            const int hh = (c >> 6) & 3;
            const int dh = c & 63;
            const int d2 = dh >> 1;
            const bool isQ = (c < 256);
            const bool ev  = ((dh & 1) == 0);
            const float bv = b_qkv[c];
            u16* dst = isQ ? Qb : Kb;
            #pragma unroll
            for (int i = 0; i < 4; ++i) {
                const int r = m0 + i * 16 + quad * 4;
                #pragma unroll
                for (int rg = 0; rg < 4; ++rg) {
                    const int t = r + rg;
                    const int n = t & 2047, b = t >> 11;
                    float v = acc[i][j][rg] + bv;
                    float pv = __shfl_xor(v, 1);
                    const float2 cs = *(const float2*)(freqs + (size_t)n * 64 + d2 * 2);
                    float o = ev ? (v * cs.x - pv * cs.y)
                                 : (pv * cs.y + v * cs.x);
                    if (isQ) o *= QSCALE;
                    dst[((size_t)(b * H_ + hh) * N_ + n) * DH_ + dh] = f2b(o);
                }
            }
        }
    } else if (by < 6) {
        // ---- V, written directly transposed: VT[bh][dh][n] (8B per store)
        #pragma unroll
        for (int j = 0; j < 4; ++j) {
            const int c  = n0 + j * 16 + ln15;      // 512..767
            const int hh = (c >> 6) & 3;
            const int dh = c & 63;
            const float bv = b_qkv[c];
            #pragma unroll
            for (int i = 0; i < 4; ++i) {
                const int r = m0 + i * 16 + quad * 4;  // r%4==0, same b for rg 0..3
                const int n = r & 2047, b = r >> 11;
                uint2 w;
                w.x = pkbf(acc[i][j][0] + bv, acc[i][j][1] + bv);
                w.y = pkbf(acc[i][j][2] + bv, acc[i][j][3] + bv);
                *(uint2*)(VT + ((size_t)(b * H_ + hh) * DH_ + dh) * N_ + n) = w;
            }
        }
    } else {
        // ---- gate: sigmoid -> gatb[t][256]
        #pragma unroll
        for (int j = 0; j < 4; ++j) {
            const int c  = n0 + j * 16 + ln15;      // 768..1023
            const int cg = c - 768;
            const float bv = b_gate[cg];
            #pragma unroll
            for (int i = 0; i < 4; ++i) {
                const int r = m0 + i * 16 + quad * 4;
                #pragma unroll
                for (int rg = 0; rg < 4; ++rg) {
                    float v = acc[i][j][rg] + bv;
                    gatb[(size_t)(r + rg) * 256 + cg] = f2b(1.0f / (1.0f + __expf(-v)));
                }
            }
        }
    }
}

// -------- fused: zc-RMSNorm (blocks 0..2047) + weight transpose (2048..3071)
__global__ __launch_bounds__(256) void norm_transw_k(
    const float* __restrict__ x, const float* __restrict__ g, u16* __restrict__ h,
    const float* __restrict__ wqkv, const float* __restrict__ wout,
    const float* __restrict__ wgate,
    u16* __restrict__ wqkvT, u16* __restrict__ woutT, u16* __restrict__ wgateT)
{
    if (blockIdx.x < 2048) {
        const int wave = threadIdx.x >> 6, lane = threadIdx.x & 63;
        const int t = blockIdx.x * 4 + wave;
        const float4 u = *(const float4*)(x + (size_t)t * D_ + lane * 4);
        float s  = u.x + u.y + u.z + u.w;
        float s2 = u.x * u.x + u.y * u.y + u.z * u.z + u.w * u.w;
        #pragma unroll
        for (int m = 1; m < 64; m <<= 1) {
            s  += __shfl_xor(s, m);
            s2 += __shfl_xor(s2, m);
        }
        float mean = s * (1.0f / D_);
        float var  = s2 * (1.0f / D_) - mean * mean;
        float rinv = rsqrtf(var + 1e-8f);
        const float4 gv = *(const float4*)(g + lane * 4);
        uint2 o;
        o.x = pkbf((u.x - mean) * rinv * gv.x, (u.y - mean) * rinv * gv.y);
        o.y = pkbf((u.z - mean) * rinv * gv.z, (u.w - mean) * rinv * gv.w);
        *(uint2*)(h + (size_t)t * D_ + lane * 4) = o;
    } else {
        int idx = (blockIdx.x - 2048) * 256 + threadIdx.x;
        if (idx < 768 * 256) {
            int nn = idx >> 8, kk = idx & 255;
            wqkvT[idx] = f2b(wqkv[kk * 768 + nn]);
        }
        idx -= 768 * 256;
        if (idx >= 0 && idx < 256 * 256) {
            int nn = idx >> 8, kk = idx & 255;
            woutT[idx]  = f2b(wout[kk * 256 + nn]);
            wgateT[idx] = f2b(wgate[kk * 256 + nn]);
        }
    }
}

// -------- flash attention, split-K x4, 32x32 MFMA, in-register softmax ------
// 4 blocks/CU exact x 4 waves = 16 waves/CU; T12 in-register softmax
// (cvt_pk + permlane32_swap), group-sequential halves for VGPR<=128.
// Round-9: partials written as bf16 (unnormalized O is lv-scaled; 0.2% rel
// error survives the /lv normalization) -> halves partial-O traffic.
__global__ __launch_bounds__(256, 4) void attn_k(
    const u16* __restrict__ Q, const u16* __restrict__ K,
    const u16* __restrict__ VT, u16* __restrict__ Opb,
    float* __restrict__ lvp)
{
    __shared__ __align__(16) u16 Ks[2][64][64];
    __shared__ __align__(16) u16 Vs[2][64][64];
    const int tid = threadIdx.x;
    const int wave = tid >> 6, lane = tid & 63;
    const int l31 = lane & 31, hi = lane >> 5;
    const int id = blockIdx.x;
    // XCD swizzle: id&7 -> fixed bh pair per XCD
    const int bh   = ((id & 7) << 1) | ((id >> 3) & 1);
    const int quar = (id >> 4) & 3;
    const int q0   = (id >> 6) * 128 + wave * 32;
    const int kt0  = quar * 512;

    const u16* Qh = Q + (size_t)bh * N_ * DH_;
    const u16* Kh = K + (size_t)bh * N_ * DH_;
    const u16* Vh = VT + (size_t)bh * DH_ * N_;

    // Q as B-operand: n = q = l31, k = kc*16 + hi*8 + j
    short8 bq[4];
    #pragma unroll
    for (int kc = 0; kc < 4; ++kc)
        bq[kc] = *(const short8*)(Qh + (size_t)(q0 + l31) * DH_ + kc * 16 + hi * 8);

    f32x16 o0, o1;   // O^T[dh 0..31][q], O^T[dh 32..63][q]
    #pragma unroll
    for (int i = 0; i < 16; ++i) { o0[i] = 0.f; o1[i] = 0.f; }
    float lv = 0.f;

    // staging: 256 threads, 2 uint4 K + 2 uint4 V each
    const int srow = tid >> 2, sq4 = tid & 3;
    const int sw = srow & 7;
    const int wg0 = ((sq4) ^ sw) * 8;          // swizzled write cols (u16)
    const int wg1 = ((sq4 + 4) ^ sw) * 8;
    const int rsw = l31 & 7;                   // read-row swizzle phase

    {
        uint4 k0 = *(const uint4*)(Kh + (size_t)(kt0 + srow) * DH_ + sq4 * 8);
        uint4 k1 = *(const uint4*)(Kh + (size_t)(kt0 + srow) * DH_ + (sq4 + 4) * 8);
        uint4 v0 = *(const uint4*)(Vh + (size_t)srow * N_ + kt0 + sq4 * 8);
        uint4 v1 = *(const uint4*)(Vh + (size_t)srow * N_ + kt0 + (sq4 + 4) * 8);
        *(uint4*)&Ks[0][srow][wg0] = k0;
        *(uint4*)&Ks[0][srow][wg1] = k1;
        *(uint4*)&Vs[0][srow][wg0] = v0;
        *(uint4*)&Vs[0][srow][wg1] = v1;
    }
    __syncthreads();

    int p = 0;
    for (int c = 0; c < 8; ++c) {
        const bool more = (c + 1 < 8);
        uint4 k0, k1, v0, v1;
        if (more) {
            const int ktn = kt0 + (c + 1) * 64;
            k0 = *(const uint4*)(Kh + (size_t)(ktn + srow) * DH_ + sq4 * 8);
            k1 = *(const uint4*)(Kh + (size_t)(ktn + srow) * DH_ + (sq4 + 4) * 8);
            v0 = *(const uint4*)(Vh + (size_t)srow * N_ + ktn + sq4 * 8);
            v1 = *(const uint4*)(Vh + (size_t)srow * N_ + ktn + (sq4 + 4) * 8);
        }

        // group-sequential: keys 32g..32g+31 (g = key-row group)
        #pragma unroll
        for (int g = 0; g < 2; ++g) {
            // QK^T: S^T[key][q]; A = K rows (32g + l31), B = Q
            f32x16 st;
            #pragma unroll
            for (int i = 0; i < 16; ++i) st[i] = 0.f;
            #pragma unroll
            for (int kc = 0; kc < 4; ++kc) {
                const int gran = ((2 * kc + hi) ^ rsw) * 8;
                short8 ka = *(const short8*)&Ks[p][g * 32 + l31][gran];
                st = mfma32(ka, bq[kc], st);
            }
            // softmax numerator in place (no running max; QSCALE pre-applied)
            #pragma unroll
            for (int r = 0; r < 16; ++r) {
                st[r] = exp2f(st[r]);
                lv += st[r];
            }
            // pack P into PV B-fragments (T12: cvt_pk + permlane32_swap)
            #pragma unroll
            for (int kc2 = 0; kc2 < 2; ++kc2) {
                u32 X0, X1, Y0, Y1;
                asm("v_cvt_pk_bf16_f32 %0, %1, %2" : "=v"(X0) : "v"(st[8*kc2+0]), "v"(st[8*kc2+1]));
                asm("v_cvt_pk_bf16_f32 %0, %1, %2" : "=v"(X1) : "v"(st[8*kc2+2]), "v"(st[8*kc2+3]));
                asm("v_cvt_pk_bf16_f32 %0, %1, %2" : "=v"(Y0) : "v"(st[8*kc2+4]), "v"(st[8*kc2+5]));
                asm("v_cvt_pk_bf16_f32 %0, %1, %2" : "=v"(Y1) : "v"(st[8*kc2+6]), "v"(st[8*kc2+7]));
                asm("v_permlane32_swap_b32 %0, %1" : "+v"(X0), "+v"(Y0));
                asm("v_permlane32_swap_b32 %0, %1" : "+v"(X1), "+v"(Y1));
                union { u32 u[4]; short8 s; } bf;
                bf.u[0] = X0; bf.u[1] = X1; bf.u[2] = Y0; bf.u[3] = Y1;
                // PV for key-chunk kc = 2g + kc2 (keys 16kc+0..15)
                const int gran = ((2 * (2 * g + kc2) + hi) ^ rsw) * 8;
                short8 va0 = *(const short8*)&Vs[p][l31][gran];
                short8 va1 = *(const short8*)&Vs[p][32 + l31][gran];
                o0 = mfma32(va0, bf.s, o0);
                o1 = mfma32(va1, bf.s, o1);
            }
        }

        if (more) {
            *(uint4*)&Ks[p ^ 1][srow][wg0] = k0;
            *(uint4*)&Ks[p ^ 1][srow][wg1] = k1;
            *(uint4*)&Vs[p ^ 1][srow][wg0] = v0;
            *(uint4*)&Vs[p ^ 1][srow][wg1] = v1;
        }
        __syncthreads();
        p ^= 1;
    }

    lv += __shfl_xor(lv, 32);
    // bf16 unnormalized partials: Opb[quar*16+bh][q][dh]
    const size_t rowo = ((size_t)(quar * 16 + bh) * N_ + q0 + l31) * DH_;
    #pragma unroll
    for (int go = 0; go < 2; ++go) {
        #pragma unroll
        for (int rq = 0; rq < 4; ++rq) {
            uint2 w;
            if (go == 0) {
                w.x = pkbf(o0[rq*4+0], o0[rq*4+1]);
                w.y = pkbf(o0[rq*4+2], o0[rq*4+3]);
            } else {
                w.x = pkbf(o1[rq*4+0], o1[rq*4+1]);
                w.y = pkbf(o1[rq*4+2], o1[rq*4+3]);
            }
            *(uint2*)(Opb + rowo + go * 32 + 8 * rq + 4 * hi) = w;
        }
    }
    if (hi == 0) lvp[(size_t)(quar * 16 + bh) * N_ + q0 + l31] = lv;
}

// -------- fused combine + out-projection (replaces combine_k + gemm_thin) --
// Round-9: combine wrote yt (4 MB) only for gemm_thin to re-read it — fuse.
// Block = 16 rows x 256 cols. Phase 1: combine 4 bf16 partials + lv sums into
// LDS As[16][264] (pad-264: row stride 528B = 4-bank offset/row -> conflict-
// free A reads). Phase 2: 4 waves x (16x64) GEMM, A from LDS (shared), B from
// L2. Epilogue: out = x + gate*(acc+bias). Grid 512 = 2 blocks/CU.
__global__ __launch_bounds__(256) void gemm_out(
    const u16* __restrict__ Opb, const float* __restrict__ lvp,
    const u16* __restrict__ BT, const float* __restrict__ bias,
    float* __restrict__ out, const float* __restrict__ xin,
    const u16* __restrict__ gate)
{
    __shared__ __align__(16) u16 As[16][264];
    const int tid = threadIdx.x;
    const int m0 = blockIdx.x * 16;

    // ---- phase 1: combine partials -> As
    {
        const int r  = tid >> 4;            // 0..15
        const int kc = (tid & 15) * 16;     // 16-aligned col in [0,256)
        const int t  = m0 + r;
        const int n  = t & 2047, b = t >> 11;
        const int h  = kc >> 6;
        const int bh = b * 4 + h;
        const int dh = kc & 63;
        float a[16];
        #pragma unroll
        for (int i = 0; i < 16; ++i) a[i] = 0.f;
        float lsum = 0.f;
        #pragma unroll
        for (int pp = 0; pp < 4; ++pp) {
            const size_t base = ((size_t)(pp * 16 + bh) * N_ + n) * DH_ + dh;
            const uint4 u0 = *(const uint4*)(Opb + base);
            const uint4 u1 = *(const uint4*)(Opb + base + 8);
            const u32 uu[8] = {u0.x, u0.y, u0.z, u0.w, u1.x, u1.y, u1.z, u1.w};
            #pragma unroll
            for (int i2 = 0; i2 < 8; ++i2) {
                a[i2 * 2]     += b2f((u16)(uu[i2] & 0xffff));
                a[i2 * 2 + 1] += b2f((u16)(uu[i2] >> 16));
            }
            lsum += lvp[(size_t)(pp * 16 + bh) * N_ + n];
        }
        const float rl = 1.0f / lsum;
        uint4 w0, w1;
        w0.x = pkbf(a[0] * rl,  a[1] * rl);  w0.y = pkbf(a[2] * rl,  a[3] * rl);
        w0.z = pkbf(a[4] * rl,  a[5] * rl);  w0.w = pkbf(a[6] * rl,  a[7] * rl);
        w1.x = pkbf(a[8] * rl,  a[9] * rl);  w1.y = pkbf(a[10] * rl, a[11] * rl);
        w1.z = pkbf(a[12] * rl, a[13] * rl); w1.w = pkbf(a[14] * rl, a[15] * rl);
        *(uint4*)&As[r][kc]     = w0;
        *(uint4*)&As[r][kc + 8] = w1;
    }
    __syncthreads();

    // ---- phase 2: GEMM 16 x 64 per wave
    const int wave = tid >> 6, lane = tid & 63;
    const int ln15 = lane & 15, quad = lane >> 4;
    const int n0 = wave * 64;
    const f32x4 zero = {0.f, 0.f, 0.f, 0.f};
    f32x4 acc[4] = {zero, zero, zero, zero};

    #pragma unroll
    for (int k0 = 0; k0 < 256; k0 += 32) {
        const int koff = k0 + quad * 8;
        const short8 a = *(const short8*)&As[ln15][koff];
        #pragma unroll
        for (int j = 0; j < 4; ++j) {
            const short8 bfr = *(const short8*)(BT + (size_t)(n0 + j * 16 + ln15) * 256 + koff);
            acc[j] = mfma16(a, bfr, acc[j]);
        }
    }

    #pragma unroll
    for (int j = 0; j < 4; ++j) {
        const int c = n0 + j * 16 + ln15;
        const float bv = bias[c];
        const int r = quad * 4;
        #pragma unroll
        for (int rg = 0; rg < 4; ++rg) {
            const size_t idx = (size_t)(m0 + r + rg) * 256 + c;
            out[idx] = xin[idx] + b2f(gate[idx]) * (acc[j][rg] + bv);
        }
    }
}

extern "C" void kernel_launch(void* const* d_in, const int* in_sizes, int n_in,
                              void* d_out, int out_size, void* d_ws, size_t ws_size,
                              hipStream_t stream) {
    const float* x      = (const float*)d_in[0];
    const float* freqs  = (const float*)d_in[1];
    const float* g      = (const float*)d_in[2];
    const float* w_qkv  = (const float*)d_in[3];
    const float* b_qkv  = (const float*)d_in[4];
    const float* w_out  = (const float*)d_in[5];
    const float* b_out  = (const float*)d_in[6];
    const float* w_gate = (const float*)d_in[7];
    const float* b_gate = (const float*)d_in[8];
    float* out = (float*)d_out;          // f32 output

    char* ws = (char*)d_ws;
    size_t off = 0;
    auto carve = [&](size_t nelem) -> u16* {
        u16* p = (u16*)(ws + off);
        off += ((nelem * 2 + 255) / 256) * 256;
        return p;
    };
    u16* h      = carve((size_t)BN_ * D_);       // bf16 (4 MB)
    u16* Qb     = carve((size_t)BN_ * D_);       // [B,H,N,DH]
    u16* Kb     = carve((size_t)BN_ * D_);
    u16* VT     = carve((size_t)BN_ * D_);       // [B,H,DH,N]
    u16* gatb   = carve((size_t)BN_ * D_);
    // wcatT = [wqkvT (768 rows) | wgateT (256 rows)] contiguous, then woutT
    u16* wqkvT  = carve((size_t)768 * 256);
    u16* wgateT = carve((size_t)256 * 256);      // = wqkvT + 768*256
    u16* woutT  = carve((size_t)256 * 256);
    // split-K x4 partials (bf16 O + f32 lv):
    u16*   Opb = carve((size_t)4 * 16 * N_ * DH_);              // 16 MB bf16
    float* lvp = (float*)carve((size_t)4 * 16 * N_ * 2);        // 512 KB f32

    hipLaunchKernelGGL(norm_transw_k, dim3(3072), dim3(256), 0, stream,
                       x, g, h, w_qkv, w_out, w_gate, wqkvT, woutT, wgateT);
    hipLaunchKernelGGL(gemm_front, dim3(64, 8), dim3(256), 0, stream,
                       h, wqkvT, b_qkv, b_gate, freqs, Qb, Kb, VT, gatb);
    hipLaunchKernelGGL(attn_k, dim3(1024), dim3(256), 0, stream,
                       Qb, Kb, VT, Opb, lvp);
    hipLaunchKernelGGL(gemm_out, dim3(512), dim3(256), 0, stream,
                       Opb, lvp, woutT, b_out, out, x, gatb);
}